// Round 1
// baseline (8048.843 us; speedup 1.0000x reference)
//
#include <hip/hip_runtime.h>

// ---------- helpers ----------
__device__ inline float bf2f(unsigned short u) {
    return __uint_as_float(((unsigned)u) << 16);
}
__device__ inline unsigned short f2bf(float f) {
    unsigned u = __float_as_uint(f);
    u += 0x7fffu + ((u >> 16) & 1u);   // round-to-nearest-even
    return (unsigned short)(u >> 16);
}

// ---------- GEMM: C[M x 128] = A[M x 128] @ W[128 x 128] (+ bias) ----------
// blockIdx.y selects relation (W += rel*16384, C += rel*M*128).
// Tile: 64 rows x 128 cols per block, 256 threads, each thread 4x8 outputs.
template <typename OutT>
__global__ __launch_bounds__(256)
void gemm128(const float* __restrict__ A, const float* __restrict__ Wg,
             const float* __restrict__ bias, OutT* __restrict__ C, int M)
{
    __shared__ float As[64][132];   // pad 132: 2-way broadcast conflicts only (free)
    __shared__ float Ws[32][132];

    const int rel = blockIdx.y;
    const float* W = Wg + (size_t)rel * 16384;
    OutT* Cb = C + (size_t)rel * (size_t)M * 128;

    const int tid = threadIdx.x;
    const int row0 = blockIdx.x * 64;

    // stage A tile (zero-pad OOB rows)
#pragma unroll
    for (int i = 0; i < 8; ++i) {
        int idx = tid + i * 256;          // 0..2047 float4s
        int rr = idx >> 5;
        int cc = (idx & 31) << 2;
        int gr = row0 + rr;
        float4 v = make_float4(0.f, 0.f, 0.f, 0.f);
        if (gr < M) v = *reinterpret_cast<const float4*>(A + (size_t)gr * 128 + cc);
        *reinterpret_cast<float4*>(&As[rr][cc]) = v;
    }

    const int tx = tid & 15;
    const int ty = tid >> 4;
    float acc[4][8];
#pragma unroll
    for (int i = 0; i < 4; ++i)
#pragma unroll
        for (int j = 0; j < 8; ++j) acc[i][j] = 0.f;

    for (int kt = 0; kt < 4; ++kt) {
        __syncthreads();
        // stage W chunk rows [kt*32, kt*32+32)
#pragma unroll
        for (int i = 0; i < 4; ++i) {
            int idx = tid + i * 256;      // 0..1023 float4s
            int rr = idx >> 5;
            int cc = (idx & 31) << 2;
            *reinterpret_cast<float4*>(&Ws[rr][cc]) =
                *reinterpret_cast<const float4*>(W + (size_t)(kt * 32 + rr) * 128 + cc);
        }
        __syncthreads();
#pragma unroll
        for (int kk = 0; kk < 32; ++kk) {
            const int k = kt * 32 + kk;
            float a0 = As[ty * 4 + 0][k];
            float a1 = As[ty * 4 + 1][k];
            float a2 = As[ty * 4 + 2][k];
            float a3 = As[ty * 4 + 3][k];
            float w[8];
#pragma unroll
            for (int j = 0; j < 8; ++j) w[j] = Ws[kk][tx * 8 + j];
#pragma unroll
            for (int j = 0; j < 8; ++j) {
                acc[0][j] = fmaf(a0, w[j], acc[0][j]);
                acc[1][j] = fmaf(a1, w[j], acc[1][j]);
                acc[2][j] = fmaf(a2, w[j], acc[2][j]);
                acc[3][j] = fmaf(a3, w[j], acc[3][j]);
            }
        }
    }

    float bb[8];
#pragma unroll
    for (int j = 0; j < 8; ++j) bb[j] = bias ? bias[tx * 8 + j] : 0.f;

#pragma unroll
    for (int i = 0; i < 4; ++i) {
        int gr = row0 + ty * 4 + i;
        if (gr >= M) continue;
        if constexpr (sizeof(OutT) == 4) {  // float output
            float4 o0 = make_float4(acc[i][0] + bb[0], acc[i][1] + bb[1],
                                    acc[i][2] + bb[2], acc[i][3] + bb[3]);
            float4 o1 = make_float4(acc[i][4] + bb[4], acc[i][5] + bb[5],
                                    acc[i][6] + bb[6], acc[i][7] + bb[7]);
            float4* cp = reinterpret_cast<float4*>((float*)Cb + (size_t)gr * 128 + tx * 8);
            cp[0] = o0;
            cp[1] = o1;
        } else {                            // bf16 output packed as uint4
            unsigned p[4];
#pragma unroll
            for (int j = 0; j < 4; ++j) {
                unsigned lo = f2bf(acc[i][2 * j] + bb[2 * j]);
                unsigned hi = f2bf(acc[i][2 * j + 1] + bb[2 * j + 1]);
                p[j] = lo | (hi << 16);
            }
            uint4* cp = reinterpret_cast<uint4*>((unsigned short*)Cb + (size_t)gr * 128 + tx * 8);
            *cp = make_uint4(p[0], p[1], p[2], p[3]);
        }
    }
}

// ---------- BatchNorm (training-mode batch stats) ----------
__global__ __launch_bounds__(256)
void bn_stats(const float* __restrict__ h, float* __restrict__ sums, int Nn)
{
    const int c = threadIdx.x & 127;
    const int half = threadIdx.x >> 7;
    float s = 0.f, q = 0.f;
    for (int row = blockIdx.x * 2 + half; row < Nn; row += gridDim.x * 2) {
        float v = h[(size_t)row * 128 + c];
        s += v;
        q += v * v;
    }
    __shared__ float ls[256], lq[256];
    ls[threadIdx.x] = s;
    lq[threadIdx.x] = q;
    __syncthreads();
    if (half == 0) {
        s += ls[threadIdx.x + 128];
        q += lq[threadIdx.x + 128];
        atomicAdd(&sums[c], s);
        atomicAdd(&sums[128 + c], q);
    }
}

__global__ void bn_finalize(const float* __restrict__ sums, const float* __restrict__ g,
                            const float* __restrict__ b, float* __restrict__ sc, int Nn)
{
    int c = threadIdx.x;  // 128 threads
    float inv = 1.f / (float)Nn;
    float mu = sums[c] * inv;
    float var = sums[128 + c] * inv - mu * mu;
    float rstd = rsqrtf(var + 1e-5f);
    float scale = rstd * g[c];
    sc[c] = scale;
    sc[128 + c] = b[c] - mu * scale;
}

__global__ __launch_bounds__(256)
void bn_apply_relu(float* __restrict__ h, const float* __restrict__ sc, size_t n4)
{
    size_t i = (size_t)blockIdx.x * 256 + threadIdx.x;
    if (i >= n4) return;
    int c = (int)(i & 31) << 2;
    float4 v = reinterpret_cast<float4*>(h)[i];
    v.x = fmaxf(fmaf(v.x, sc[c + 0], sc[128 + c + 0]), 0.f);
    v.y = fmaxf(fmaf(v.y, sc[c + 1], sc[128 + c + 1]), 0.f);
    v.z = fmaxf(fmaf(v.z, sc[c + 2], sc[128 + c + 2]), 0.f);
    v.w = fmaxf(fmaf(v.w, sc[c + 3], sc[128 + c + 3]), 0.f);
    reinterpret_cast<float4*>(h)[i] = v;
}

// ---------- degree / gcn norm ----------
__global__ __launch_bounds__(256)
void deg_kernel(const int* __restrict__ ei, int* __restrict__ deg, int E)
{
    int e = blockIdx.x * 256 + threadIdx.x;
    if (e < E) atomicAdd(&deg[ei[E + e]], 1);   // deg over src column
}

__global__ __launch_bounds__(256)
void dis_kernel(const int* __restrict__ deg, float* __restrict__ dis, int Nn)
{
    int n = blockIdx.x * 256 + threadIdx.x;
    if (n < Nn) {
        int d = deg[n];
        dis[n] = d > 0 ? rsqrtf((float)d) : 0.f;
    }
}

// ---------- fused edge pass ----------
// 32 threads per edge, 4 channels each.
// mg  += xlin[src]*norm      (gcn message)
// s   += exp(res)            (softmax denom; max-shift dropped: |res| << 88)
// t   += res*exp(res)        (softmax numerator)
__global__ __launch_bounds__(256)
void edge_pass(const int* __restrict__ ei, const int* __restrict__ et,
               const float* __restrict__ dis, const float* __restrict__ xlin,
               const unsigned short* __restrict__ Y,
               float* __restrict__ mg, float* __restrict__ sb, float* __restrict__ tb,
               int E, int Nn)
{
    int gid = blockIdx.x * 256 + threadIdx.x;
    int e = gid >> 5;
    if (e >= E) return;
    int c = (gid & 31) << 2;
    int dst = ei[e];
    int src = ei[E + e];
    int r = et[e];
    float nrm = dis[dst] * dis[src];
    const float4 x = *reinterpret_cast<const float4*>(xlin + (size_t)src * 128 + c);
    const ushort4 y4 = *reinterpret_cast<const ushort4*>(Y + ((size_t)r * Nn + src) * 128 + c);
    float y0 = bf2f(y4.x), y1 = bf2f(y4.y), y2 = bf2f(y4.z), y3 = bf2f(y4.w);
    float w0 = __expf(y0), w1 = __expf(y1), w2 = __expf(y2), w3 = __expf(y3);
    size_t db = (size_t)dst * 128 + c;
    atomicAdd(&mg[db + 0], x.x * nrm);
    atomicAdd(&mg[db + 1], x.y * nrm);
    atomicAdd(&mg[db + 2], x.z * nrm);
    atomicAdd(&mg[db + 3], x.w * nrm);
    atomicAdd(&sb[db + 0], w0);
    atomicAdd(&sb[db + 1], w1);
    atomicAdd(&sb[db + 2], w2);
    atomicAdd(&sb[db + 3], w3);
    atomicAdd(&tb[db + 0], y0 * w0);
    atomicAdd(&tb[db + 1], y1 * w1);
    atomicAdd(&tb[db + 2], y2 * w2);
    atomicAdd(&tb[db + 3], y3 * w3);
}

// ---------- combine: mg += 0.1*relu(t/s) ----------
__global__ __launch_bounds__(256)
void combine(float* __restrict__ mg, const float* __restrict__ s,
             const float* __restrict__ t, size_t n4)
{
    size_t i = (size_t)blockIdx.x * 256 + threadIdx.x;
    if (i >= n4) return;
    float4 mv = reinterpret_cast<float4*>(mg)[i];
    float4 sv = reinterpret_cast<const float4*>(s)[i];
    float4 tv = reinterpret_cast<const float4*>(t)[i];
    mv.x += 0.1f * fmaxf(sv.x > 0.f ? tv.x / sv.x : 0.f, 0.f);
    mv.y += 0.1f * fmaxf(sv.y > 0.f ? tv.y / sv.y : 0.f, 0.f);
    mv.z += 0.1f * fmaxf(sv.z > 0.f ? tv.z / sv.z : 0.f, 0.f);
    mv.w += 0.1f * fmaxf(sv.w > 0.f ? tv.w / sv.w : 0.f, 0.f);
    reinterpret_cast<float4*>(mg)[i] = mv;
}

// ---------- gather rows + exact gelu ----------
__global__ __launch_bounds__(256)
void gather_gelu(const float* __restrict__ h, const int* __restrict__ idx,
                 float* __restrict__ out, int M)
{
    int i = blockIdx.x * 256 + threadIdx.x;
    if (i >= M * 32) return;
    int row = i >> 5;
    int c = (i & 31) << 2;
    float4 v = *reinterpret_cast<const float4*>(h + (size_t)idx[row] * 128 + c);
    const float k = 0.7071067811865475f;
    v.x = 0.5f * v.x * (1.f + erff(v.x * k));
    v.y = 0.5f * v.y * (1.f + erff(v.y * k));
    v.z = 0.5f * v.z * (1.f + erff(v.z * k));
    v.w = 0.5f * v.w * (1.f + erff(v.w * k));
    reinterpret_cast<float4*>(out)[i] = v;
}

// ---------- launch ----------
extern "C" void kernel_launch(void* const* d_in, const int* in_sizes, int n_in,
                              void* d_out, int out_size, void* d_ws, size_t ws_size,
                              hipStream_t stream)
{
    const float* x      = (const float*)d_in[0];
    const int*   ei     = (const int*)d_in[1];
    const int*   et     = (const int*)d_in[2];
    // d_in[3] edge_weight: unused by the reference
    const int*   idxp   = (const int*)d_in[4];
    const float* proj_w = (const float*)d_in[5];
    const float* proj_b = (const float*)d_in[6];
    const float* bn_g   = (const float*)d_in[7];
    const float* bn_b   = (const float*)d_in[8];
    const float* win_w[2]  = {(const float*)d_in[9],  (const float*)d_in[14]};
    const float* win_b[2]  = {(const float*)d_in[10], (const float*)d_in[15]};
    const float* wrel[2]   = {(const float*)d_in[11], (const float*)d_in[16]};
    const float* cout_w[2] = {(const float*)d_in[12], (const float*)d_in[17]};
    const float* cout_b[2] = {(const float*)d_in[13], (const float*)d_in[18]};

    const int Nn  = in_sizes[0] / 128;
    const int E   = in_sizes[1] / 2;
    const int Mo  = in_sizes[4];
    const int nrel = in_sizes[11] / (128 * 128);
    const size_t ND = (size_t)Nn * 128;

    // workspace layout (~190 MB)
    char* p = (char*)d_ws;
    float* h   = (float*)p;                   p += ND * 4;
    float* tmp = (float*)p;                   p += ND * 4;           // xlin
    unsigned short* Yb = (unsigned short*)p;  p += (size_t)nrel * ND * 2;
    float* mg  = (float*)p;                   p += ND * 4;
    float* sb  = (float*)p;                   p += ND * 4;
    float* tb  = (float*)p;                   p += ND * 4;
    float* dis = (float*)p;                   p += (size_t)Nn * 4;
    int*   deg = (int*)p;                     p += (size_t)Nn * 4;
    float* bnsums = (float*)p;                p += 256 * 4;
    float* bnsc   = (float*)p;                p += 256 * 4;
    if ((size_t)(p - (char*)d_ws) > ws_size) return;  // insufficient workspace

    const int gemmGrid = (Nn + 63) / 64;
    const size_t n4 = ND / 4;
    const int n4grid = (int)((n4 + 255) / 256);
    const int egrid = (int)(((size_t)E * 32 + 255) / 256);

    // stage 0: proj -> BN(batch stats) -> relu ; degree norm
    gemm128<float><<<dim3(gemmGrid, 1), 256, 0, stream>>>(x, proj_w, proj_b, h, Nn);
    hipMemsetAsync(bnsums, 0, 256 * 4, stream);
    hipMemsetAsync(deg, 0, (size_t)Nn * 4, stream);
    bn_stats<<<512, 256, 0, stream>>>(h, bnsums, Nn);
    bn_finalize<<<1, 128, 0, stream>>>(bnsums, bn_g, bn_b, bnsc, Nn);
    bn_apply_relu<<<n4grid, 256, 0, stream>>>(h, bnsc, n4);
    deg_kernel<<<(E + 255) / 256, 256, 0, stream>>>(ei, deg, E);
    dis_kernel<<<(Nn + 255) / 256, 256, 0, stream>>>(deg, dis, Nn);

    for (int l = 0; l < 2; ++l) {
        // xlin = h @ win + b
        gemm128<float><<<dim3(gemmGrid, 1), 256, 0, stream>>>(h, win_w[l], win_b[l], tmp, Nn);
        // Y[r] = xlin @ wrel[r]  (bf16 storage)
        gemm128<unsigned short><<<dim3(gemmGrid, nrel), 256, 0, stream>>>(tmp, wrel[l], nullptr, Yb, Nn);
        // zero accumulators (mg, sb, tb contiguous)
        hipMemsetAsync(mg, 0, ND * 4 * 3, stream);
        // fused edge pass: gcn-sum + softmax sums
        edge_pass<<<egrid, 256, 0, stream>>>(ei, et, dis, tmp, Yb, mg, sb, tb, E, Nn);
        // mg += 0.1*relu(t/s)
        combine<<<n4grid, 256, 0, stream>>>(mg, sb, tb, n4);
        // h = mg @ cout + b
        gemm128<float><<<dim3(gemmGrid, 1), 256, 0, stream>>>(mg, cout_w[l], cout_b[l], h, Nn);
    }

    gather_gelu<<<(Mo * 32 + 255) / 256, 256, 0, stream>>>(h, idxp, (float*)d_out, Mo);
}

// Round 2
// 786.029 us; speedup vs baseline: 10.2399x; 10.2399x over previous
//
#include <hip/hip_runtime.h>

// ---------- helpers ----------
__device__ inline float bf2f(unsigned short u) {
    return __uint_as_float(((unsigned)u) << 16);
}
__device__ inline unsigned short f2bf(float f) {
    unsigned u = __float_as_uint(f);
    u += 0x7fffu + ((u >> 16) & 1u);   // round-to-nearest-even
    return (unsigned short)(u >> 16);
}

// ---------- GEMM: C[M x 128] = A[M x 128] @ W[128 x 128] (+ bias) ----------
// blockIdx.y selects relation (W += rel*16384, C += rel*M*128).
// Tile: 64 rows x 128 cols per block, 256 threads, each thread 4x8 outputs.
template <typename OutT>
__global__ __launch_bounds__(256)
void gemm128(const float* __restrict__ A, const float* __restrict__ Wg,
             const float* __restrict__ bias, OutT* __restrict__ C, int M)
{
    __shared__ float As[64][132];
    __shared__ float Ws[32][132];

    const int rel = blockIdx.y;
    const float* W = Wg + (size_t)rel * 16384;
    OutT* Cb = C + (size_t)rel * (size_t)M * 128;

    const int tid = threadIdx.x;
    const int row0 = blockIdx.x * 64;

#pragma unroll
    for (int i = 0; i < 8; ++i) {
        int idx = tid + i * 256;
        int rr = idx >> 5;
        int cc = (idx & 31) << 2;
        int gr = row0 + rr;
        float4 v = make_float4(0.f, 0.f, 0.f, 0.f);
        if (gr < M) v = *reinterpret_cast<const float4*>(A + (size_t)gr * 128 + cc);
        *reinterpret_cast<float4*>(&As[rr][cc]) = v;
    }

    const int tx = tid & 15;
    const int ty = tid >> 4;
    float acc[4][8];
#pragma unroll
    for (int i = 0; i < 4; ++i)
#pragma unroll
        for (int j = 0; j < 8; ++j) acc[i][j] = 0.f;

    for (int kt = 0; kt < 4; ++kt) {
        __syncthreads();
#pragma unroll
        for (int i = 0; i < 4; ++i) {
            int idx = tid + i * 256;
            int rr = idx >> 5;
            int cc = (idx & 31) << 2;
            *reinterpret_cast<float4*>(&Ws[rr][cc]) =
                *reinterpret_cast<const float4*>(W + (size_t)(kt * 32 + rr) * 128 + cc);
        }
        __syncthreads();
#pragma unroll
        for (int kk = 0; kk < 32; ++kk) {
            const int k = kt * 32 + kk;
            float a0 = As[ty * 4 + 0][k];
            float a1 = As[ty * 4 + 1][k];
            float a2 = As[ty * 4 + 2][k];
            float a3 = As[ty * 4 + 3][k];
            float w[8];
#pragma unroll
            for (int j = 0; j < 8; ++j) w[j] = Ws[kk][tx * 8 + j];
#pragma unroll
            for (int j = 0; j < 8; ++j) {
                acc[0][j] = fmaf(a0, w[j], acc[0][j]);
                acc[1][j] = fmaf(a1, w[j], acc[1][j]);
                acc[2][j] = fmaf(a2, w[j], acc[2][j]);
                acc[3][j] = fmaf(a3, w[j], acc[3][j]);
            }
        }
    }

    float bb[8];
#pragma unroll
    for (int j = 0; j < 8; ++j) bb[j] = bias ? bias[tx * 8 + j] : 0.f;

#pragma unroll
    for (int i = 0; i < 4; ++i) {
        int gr = row0 + ty * 4 + i;
        if (gr >= M) continue;
        if constexpr (sizeof(OutT) == 4) {
            float4 o0 = make_float4(acc[i][0] + bb[0], acc[i][1] + bb[1],
                                    acc[i][2] + bb[2], acc[i][3] + bb[3]);
            float4 o1 = make_float4(acc[i][4] + bb[4], acc[i][5] + bb[5],
                                    acc[i][6] + bb[6], acc[i][7] + bb[7]);
            float4* cp = reinterpret_cast<float4*>((float*)Cb + (size_t)gr * 128 + tx * 8);
            cp[0] = o0;
            cp[1] = o1;
        } else {
            unsigned p[4];
#pragma unroll
            for (int j = 0; j < 4; ++j) {
                unsigned lo = f2bf(acc[i][2 * j] + bb[2 * j]);
                unsigned hi = f2bf(acc[i][2 * j + 1] + bb[2 * j + 1]);
                p[j] = lo | (hi << 16);
            }
            uint4* cp = reinterpret_cast<uint4*>((unsigned short*)Cb + (size_t)gr * 128 + tx * 8);
            *cp = make_uint4(p[0], p[1], p[2], p[3]);
        }
    }
}

// ---------- BatchNorm (training-mode batch stats) ----------
__global__ __launch_bounds__(256)
void bn_stats(const float* __restrict__ h, float* __restrict__ sums, int Nn)
{
    const int c = threadIdx.x & 127;
    const int half = threadIdx.x >> 7;
    float s = 0.f, q = 0.f;
    for (int row = blockIdx.x * 2 + half; row < Nn; row += gridDim.x * 2) {
        float v = h[(size_t)row * 128 + c];
        s += v;
        q += v * v;
    }
    __shared__ float ls[256], lq[256];
    ls[threadIdx.x] = s;
    lq[threadIdx.x] = q;
    __syncthreads();
    if (half == 0) {
        s += ls[threadIdx.x + 128];
        q += lq[threadIdx.x + 128];
        atomicAdd(&sums[c], s);
        atomicAdd(&sums[128 + c], q);
    }
}

__global__ void bn_finalize(const float* __restrict__ sums, const float* __restrict__ g,
                            const float* __restrict__ b, float* __restrict__ sc, int Nn)
{
    int c = threadIdx.x;  // 128 threads
    float inv = 1.f / (float)Nn;
    float mu = sums[c] * inv;
    float var = sums[128 + c] * inv - mu * mu;
    float rstd = rsqrtf(var + 1e-5f);
    float scale = rstd * g[c];
    sc[c] = scale;
    sc[128 + c] = b[c] - mu * scale;
}

__global__ __launch_bounds__(256)
void bn_apply_relu(float* __restrict__ h, const float* __restrict__ sc, size_t n4)
{
    size_t i = (size_t)blockIdx.x * 256 + threadIdx.x;
    if (i >= n4) return;
    int c = (int)(i & 31) << 2;
    float4 v = reinterpret_cast<float4*>(h)[i];
    v.x = fmaxf(fmaf(v.x, sc[c + 0], sc[128 + c + 0]), 0.f);
    v.y = fmaxf(fmaf(v.y, sc[c + 1], sc[128 + c + 1]), 0.f);
    v.z = fmaxf(fmaf(v.z, sc[c + 2], sc[128 + c + 2]), 0.f);
    v.w = fmaxf(fmaf(v.w, sc[c + 3], sc[128 + c + 3]), 0.f);
    reinterpret_cast<float4*>(h)[i] = v;
}

// ---------- degree counts (src for gcn-norm, dst for CSR) ----------
__global__ __launch_bounds__(256)
void deg_kernel(const int* __restrict__ ei, int* __restrict__ degsrc,
                int* __restrict__ cntdst, int E)
{
    int e = blockIdx.x * 256 + threadIdx.x;
    if (e < E) {
        atomicAdd(&degsrc[ei[E + e]], 1);
        atomicAdd(&cntdst[ei[e]], 1);
    }
}

__global__ __launch_bounds__(256)
void dis_kernel(const int* __restrict__ deg, float* __restrict__ dis, int Nn)
{
    int n = blockIdx.x * 256 + threadIdx.x;
    if (n < Nn) {
        int d = deg[n];
        dis[n] = d > 0 ? rsqrtf((float)d) : 0.f;
    }
}

// ---------- CSR build: 2-level exclusive scan + scatter ----------
__global__ __launch_bounds__(256)
void scan_block_sums(const int* __restrict__ cnt, int* __restrict__ bsum, int Nn)
{
    __shared__ int sd[256];
    int tid = threadIdx.x;
    int i = blockIdx.x * 256 + tid;
    sd[tid] = i < Nn ? cnt[i] : 0;
    __syncthreads();
#pragma unroll
    for (int s = 128; s > 0; s >>= 1) {
        if (tid < s) sd[tid] += sd[tid + s];
        __syncthreads();
    }
    if (tid == 0) bsum[blockIdx.x] = sd[0];
}

__global__ __launch_bounds__(1024)
void scan_offsets(int* __restrict__ bsum, int nb)   // nb <= 1024
{
    __shared__ int sd[1024];
    int tid = threadIdx.x;
    int v = tid < nb ? bsum[tid] : 0;
    sd[tid] = v;
    __syncthreads();
    for (int d = 1; d < 1024; d <<= 1) {
        int t = 0;
        if (tid >= d) t = sd[tid - d];
        __syncthreads();
        sd[tid] += t;
        __syncthreads();
    }
    if (tid < nb) bsum[tid] = sd[tid] - v;   // exclusive
}

__global__ __launch_bounds__(256)
void scan_final(const int* __restrict__ cnt, const int* __restrict__ bsum,
                int* __restrict__ rowptr, int Nn, int E)
{
    __shared__ int sd[256];
    int tid = threadIdx.x;
    int i = blockIdx.x * 256 + tid;
    int v = i < Nn ? cnt[i] : 0;
    sd[tid] = v;
    __syncthreads();
    for (int d = 1; d < 256; d <<= 1) {
        int t = 0;
        if (tid >= d) t = sd[tid - d];
        __syncthreads();
        sd[tid] += t;
        __syncthreads();
    }
    if (i < Nn) rowptr[i] = sd[tid] - v + bsum[blockIdx.x];
    if (blockIdx.x == 0 && tid == 0) rowptr[Nn] = E;
}

__global__ __launch_bounds__(256)
void scatter_csr(const int* __restrict__ ei, const int* __restrict__ et,
                 int* __restrict__ cursor, unsigned* __restrict__ csr, int E)
{
    int e = blockIdx.x * 256 + threadIdx.x;
    if (e < E) {
        int dst = ei[e];
        int src = ei[E + e];
        int pos = atomicAdd(&cursor[dst], 1);
        csr[pos] = (unsigned)src | ((unsigned)et[e] << 17);   // src < 2^17, type < 8
    }
}

// ---------- fused per-node gather: gcn-sum + scatter-softmax + combine ----------
// One wave (64 lanes) per dst node; lane owns channels 2l, 2l+1.
// out[node] = mg + 0.1 * relu( sum(y*e^y)/sum(e^y) )   (max-shift dropped: |y| << 88)
__global__ __launch_bounds__(256)
void node_gather(const int* __restrict__ rowptr, const unsigned* __restrict__ csr,
                 const float* __restrict__ dis, const float* __restrict__ xlin,
                 const unsigned short* __restrict__ Y,
                 float* __restrict__ out, int Nn)
{
    int node = blockIdx.x * 4 + (threadIdx.x >> 6);
    if (node >= Nn) return;
    int lane = threadIdx.x & 63;
    int c = lane << 1;

    float dd = dis[node];
    int start = rowptr[node];
    int end = rowptr[node + 1];

    float mg0 = 0.f, mg1 = 0.f, s0 = 0.f, s1 = 0.f, t0 = 0.f, t1 = 0.f;
    for (int i = start; i < end; ++i) {
        unsigned pk = csr[i];                       // wave-uniform broadcast
        int src = (int)(pk & 0x1FFFFu);
        int r = (int)(pk >> 17);
        float nrm = dd * dis[src];
        float2 x = *reinterpret_cast<const float2*>(xlin + (size_t)src * 128 + c);
        unsigned yp = *reinterpret_cast<const unsigned*>(Y + ((size_t)r * Nn + src) * 128 + c);
        float y0 = bf2f((unsigned short)(yp & 0xffffu));
        float y1 = bf2f((unsigned short)(yp >> 16));
        float w0 = __expf(y0), w1 = __expf(y1);
        mg0 = fmaf(x.x, nrm, mg0);
        mg1 = fmaf(x.y, nrm, mg1);
        s0 += w0; s1 += w1;
        t0 = fmaf(y0, w0, t0);
        t1 = fmaf(y1, w1, t1);
    }
    float o0 = mg0 + 0.1f * fmaxf(s0 > 0.f ? t0 / s0 : 0.f, 0.f);
    float o1 = mg1 + 0.1f * fmaxf(s1 > 0.f ? t1 / s1 : 0.f, 0.f);
    *reinterpret_cast<float2*>(out + (size_t)node * 128 + c) = make_float2(o0, o1);
}

// ---------- gather rows + exact gelu ----------
__global__ __launch_bounds__(256)
void gather_gelu(const float* __restrict__ h, const int* __restrict__ idx,
                 float* __restrict__ out, int M)
{
    int i = blockIdx.x * 256 + threadIdx.x;
    if (i >= M * 32) return;
    int row = i >> 5;
    int c = (i & 31) << 2;
    float4 v = *reinterpret_cast<const float4*>(h + (size_t)idx[row] * 128 + c);
    const float k = 0.7071067811865475f;
    v.x = 0.5f * v.x * (1.f + erff(v.x * k));
    v.y = 0.5f * v.y * (1.f + erff(v.y * k));
    v.z = 0.5f * v.z * (1.f + erff(v.z * k));
    v.w = 0.5f * v.w * (1.f + erff(v.w * k));
    reinterpret_cast<float4*>(out)[i] = v;
}

// ---------- launch ----------
extern "C" void kernel_launch(void* const* d_in, const int* in_sizes, int n_in,
                              void* d_out, int out_size, void* d_ws, size_t ws_size,
                              hipStream_t stream)
{
    const float* x      = (const float*)d_in[0];
    const int*   ei     = (const int*)d_in[1];
    const int*   et     = (const int*)d_in[2];
    // d_in[3] edge_weight: unused by the reference
    const int*   idxp   = (const int*)d_in[4];
    const float* proj_w = (const float*)d_in[5];
    const float* proj_b = (const float*)d_in[6];
    const float* bn_g   = (const float*)d_in[7];
    const float* bn_b   = (const float*)d_in[8];
    const float* win_w[2]  = {(const float*)d_in[9],  (const float*)d_in[14]};
    const float* win_b[2]  = {(const float*)d_in[10], (const float*)d_in[15]};
    const float* wrel[2]   = {(const float*)d_in[11], (const float*)d_in[16]};
    const float* cout_w[2] = {(const float*)d_in[12], (const float*)d_in[17]};
    const float* cout_b[2] = {(const float*)d_in[13], (const float*)d_in[18]};

    const int Nn  = in_sizes[0] / 128;
    const int E   = in_sizes[1] / 2;
    const int Mo  = in_sizes[4];
    const int nrel = in_sizes[11] / (128 * 128);
    const size_t ND = (size_t)Nn * 128;

    // workspace layout (~145 MB)
    char* p = (char*)d_ws;
    float* h    = (float*)p;                  p += ND * 4;
    float* tmp  = (float*)p;                  p += ND * 4;            // xlin
    unsigned short* Yb = (unsigned short*)p;  p += (size_t)nrel * ND * 2;
    float* msg  = (float*)p;                  p += ND * 4;
    float* dis  = (float*)p;                  p += (size_t)Nn * 4;
    int*   deg  = (int*)p;                    p += (size_t)Nn * 4;    // over src
    int*   cnt  = (int*)p;                    p += (size_t)Nn * 4;    // over dst
    int*   rowptr = (int*)p;                  p += ((size_t)Nn + 1) * 4;
    int*   cursor = (int*)p;                  p += (size_t)Nn * 4;
    unsigned* csr = (unsigned*)p;             p += (size_t)E * 4;
    int*   bsum = (int*)p;                    p += 1024 * 4;
    float* bnsums = (float*)p;                p += 256 * 4;
    float* bnsc   = (float*)p;                p += 256 * 4;
    if ((size_t)(p - (char*)d_ws) > ws_size) return;

    const int gemmGrid = (Nn + 63) / 64;
    const size_t n4 = ND / 4;
    const int n4grid = (int)((n4 + 255) / 256);
    const int nb = (Nn + 255) / 256;

    // ---- stage 0: proj -> BN(batch stats) -> relu ----
    gemm128<float><<<dim3(gemmGrid, 1), 256, 0, stream>>>(x, proj_w, proj_b, h, Nn);
    hipMemsetAsync(bnsums, 0, 256 * 4, stream);
    hipMemsetAsync(deg, 0, (size_t)Nn * 4, stream);
    hipMemsetAsync(cnt, 0, (size_t)Nn * 4, stream);
    bn_stats<<<512, 256, 0, stream>>>(h, bnsums, Nn);
    bn_finalize<<<1, 128, 0, stream>>>(bnsums, bn_g, bn_b, bnsc, Nn);
    bn_apply_relu<<<n4grid, 256, 0, stream>>>(h, bnsc, n4);

    // ---- CSR build (once; shared by both layers) ----
    deg_kernel<<<(E + 255) / 256, 256, 0, stream>>>(ei, deg, cnt, E);
    dis_kernel<<<(Nn + 255) / 256, 256, 0, stream>>>(deg, dis, Nn);
    scan_block_sums<<<nb, 256, 0, stream>>>(cnt, bsum, Nn);
    scan_offsets<<<1, 1024, 0, stream>>>(bsum, nb);
    scan_final<<<nb, 256, 0, stream>>>(cnt, bsum, rowptr, Nn, E);
    hipMemcpyAsync(cursor, rowptr, (size_t)Nn * 4, hipMemcpyDeviceToDevice, stream);
    scatter_csr<<<(E + 255) / 256, 256, 0, stream>>>(ei, et, cursor, csr, E);

    // ---- two DAN layers ----
    for (int l = 0; l < 2; ++l) {
        gemm128<float><<<dim3(gemmGrid, 1), 256, 0, stream>>>(h, win_w[l], win_b[l], tmp, Nn);
        gemm128<unsigned short><<<dim3(gemmGrid, nrel), 256, 0, stream>>>(tmp, wrel[l], nullptr, Yb, Nn);
        node_gather<<<(Nn + 3) / 4, 256, 0, stream>>>(rowptr, csr, dis, tmp, Yb, msg, Nn);
        gemm128<float><<<dim3(gemmGrid, 1), 256, 0, stream>>>(msg, cout_w[l], cout_b[l], h, Nn);
    }

    gather_gelu<<<(Mo * 32 + 255) / 256, 256, 0, stream>>>(h, idxp, (float*)d_out, Mo);
}

// Round 3
// 663.322 us; speedup vs baseline: 12.1341x; 1.1850x over previous
//
#include <hip/hip_runtime.h>

// ---------- helpers ----------
__device__ inline float bf2f(unsigned short u) {
    return __uint_as_float(((unsigned)u) << 16);
}
__device__ inline unsigned short f2bf(float f) {
    unsigned u = __float_as_uint(f);
    u += 0x7fffu + ((u >> 16) & 1u);   // round-to-nearest-even
    return (unsigned short)(u >> 16);
}

typedef __attribute__((ext_vector_type(8))) short short8v;   // 8 bf16 (4 VGPRs)
typedef __attribute__((ext_vector_type(4))) float f32x4;

// ---------- f32 GEMM: C[M x 128] = A[M x 128] @ W[128 x 128] (+ bias) ----------
// 64-row tile, 256 threads, thread = 4 rows x 8 cols. A staged in LDS
// (broadcast-only reads); W streamed from global (L1/L2-resident, no LDS,
// no bank conflicts, no K-loop barriers). Optional f32 and/or bf16 outputs.
__global__ __launch_bounds__(256)
void gemm_f32(const float* __restrict__ A, const float* __restrict__ W,
              const float* __restrict__ bias, float* __restrict__ C,
              unsigned short* __restrict__ C16, int M)
{
    __shared__ float As[64][132];

    const int tid = threadIdx.x;
    const int row0 = blockIdx.x * 64;

#pragma unroll
    for (int i = 0; i < 8; ++i) {
        int idx = tid + i * 256;
        int rr = idx >> 5;
        int cc = (idx & 31) << 2;
        int gr = row0 + rr;
        float4 v = make_float4(0.f, 0.f, 0.f, 0.f);
        if (gr < M) v = *reinterpret_cast<const float4*>(A + (size_t)gr * 128 + cc);
        *reinterpret_cast<float4*>(&As[rr][cc]) = v;
    }
    __syncthreads();

    const int tx = tid & 15;
    const int ty = tid >> 4;
    float acc[4][8];
#pragma unroll
    for (int i = 0; i < 4; ++i)
#pragma unroll
        for (int j = 0; j < 8; ++j) acc[i][j] = 0.f;

#pragma unroll 4
    for (int kk = 0; kk < 128; ++kk) {
        float a0 = As[ty * 4 + 0][kk];
        float a1 = As[ty * 4 + 1][kk];
        float a2 = As[ty * 4 + 2][kk];
        float a3 = As[ty * 4 + 3][kk];
        float4 w0 = *reinterpret_cast<const float4*>(W + (size_t)kk * 128 + tx * 8);
        float4 w1 = *reinterpret_cast<const float4*>(W + (size_t)kk * 128 + tx * 8 + 4);
        float w[8] = {w0.x, w0.y, w0.z, w0.w, w1.x, w1.y, w1.z, w1.w};
#pragma unroll
        for (int j = 0; j < 8; ++j) {
            acc[0][j] = fmaf(a0, w[j], acc[0][j]);
            acc[1][j] = fmaf(a1, w[j], acc[1][j]);
            acc[2][j] = fmaf(a2, w[j], acc[2][j]);
            acc[3][j] = fmaf(a3, w[j], acc[3][j]);
        }
    }

    float bb[8];
#pragma unroll
    for (int j = 0; j < 8; ++j) bb[j] = bias ? bias[tx * 8 + j] : 0.f;

#pragma unroll
    for (int i = 0; i < 4; ++i) {
        int gr = row0 + ty * 4 + i;
        if (gr >= M) continue;
        if (C) {
            float4 o0 = make_float4(acc[i][0] + bb[0], acc[i][1] + bb[1],
                                    acc[i][2] + bb[2], acc[i][3] + bb[3]);
            float4 o1 = make_float4(acc[i][4] + bb[4], acc[i][5] + bb[5],
                                    acc[i][6] + bb[6], acc[i][7] + bb[7]);
            float4* cp = reinterpret_cast<float4*>(C + (size_t)gr * 128 + tx * 8);
            cp[0] = o0;
            cp[1] = o1;
        }
        if (C16) {
            unsigned p[4];
#pragma unroll
            for (int j = 0; j < 4; ++j) {
                unsigned lo = f2bf(acc[i][2 * j] + bb[2 * j]);
                unsigned hi = f2bf(acc[i][2 * j + 1] + bb[2 * j + 1]);
                p[j] = lo | (hi << 16);
            }
            uint4* cp = reinterpret_cast<uint4*>(C16 + (size_t)gr * 128 + tx * 8);
            *cp = make_uint4(p[0], p[1], p[2], p[3]);
        }
    }
}

// ---------- weight transpose+convert: Wt[mat][n][k] bf16 <- W[mat][k][n] f32 ----------
__global__ __launch_bounds__(256)
void wt_convert(const float* __restrict__ W0, const float* __restrict__ W1,
                unsigned short* __restrict__ Wt, int nrel)
{
    int mat = blockIdx.x;  // 0..2*nrel-1
    const float* W = (mat < nrel) ? W0 + (size_t)mat * 16384
                                  : W1 + (size_t)(mat - nrel) * 16384;
    unsigned short* O = Wt + (size_t)mat * 16384;
    for (int i = threadIdx.x; i < 16384; i += 256) {
        int k = i >> 7, n = i & 127;
        O[(size_t)n * 128 + k] = f2bf(W[i]);
    }
}

// ---------- MFMA GEMM: Y[r] = Xb @ Wrel[r]  (bf16 in, f32 acc, bf16 out) ----------
// grid (ceil(M/128), nrel); 256 thr = 4 waves; wave owns 32 rows x 128 cols.
// 16x16x32 fragments: A row = lane&15, k-group = lane>>4 (any consistent
// k-bijection cancels between A and B); C/D: col = lane&15, row = (lane>>4)*4+reg.
__global__ __launch_bounds__(256)
void gemm_mfma_y(const unsigned short* __restrict__ Xb,
                 const unsigned short* __restrict__ Wt,
                 unsigned short* __restrict__ Y, int M)
{
    const int rel = blockIdx.y;
    const int wave = threadIdx.x >> 6;
    const int lane = threadIdx.x & 63;
    const int row0 = blockIdx.x * 128 + wave * 32;
    const int grp = lane >> 4;       // 0..3
    const int l16 = lane & 15;

    const unsigned short* Wr = Wt + (size_t)rel * 16384;
    f32x4 acc[2][8] = {};

#pragma unroll
    for (int kt = 0; kt < 4; ++kt) {
        const int k0 = kt * 32 + grp * 8;
        short8v a[2];
#pragma unroll
        for (int m = 0; m < 2; ++m) {
            int r = row0 + 16 * m + l16;
            if (r > M - 1) r = M - 1;          // clamp; tail rows not stored
            a[m] = *reinterpret_cast<const short8v*>(Xb + (size_t)r * 128 + k0);
        }
#pragma unroll
        for (int n = 0; n < 8; ++n) {
            short8v b = *reinterpret_cast<const short8v*>(Wr + (size_t)(16 * n + l16) * 128 + k0);
            acc[0][n] = __builtin_amdgcn_mfma_f32_16x16x32_bf16(a[0], b, acc[0][n], 0, 0, 0);
            acc[1][n] = __builtin_amdgcn_mfma_f32_16x16x32_bf16(a[1], b, acc[1][n], 0, 0, 0);
        }
    }

    unsigned short* Yr = Y + (size_t)rel * (size_t)M * 128;
#pragma unroll
    for (int m = 0; m < 2; ++m)
#pragma unroll
        for (int n = 0; n < 8; ++n)
#pragma unroll
            for (int r = 0; r < 4; ++r) {
                int row = row0 + 16 * m + grp * 4 + r;
                if (row < M) Yr[(size_t)row * 128 + 16 * n + l16] = f2bf(acc[m][n][r]);
            }
}

// ---------- BatchNorm (training-mode batch stats) ----------
__global__ __launch_bounds__(256)
void bn_stats(const float* __restrict__ h, float* __restrict__ sums, int Nn)
{
    const int c = threadIdx.x & 127;
    const int half = threadIdx.x >> 7;
    float s = 0.f, q = 0.f;
    for (int row = blockIdx.x * 2 + half; row < Nn; row += gridDim.x * 2) {
        float v = h[(size_t)row * 128 + c];
        s += v;
        q += v * v;
    }
    __shared__ float ls[256], lq[256];
    ls[threadIdx.x] = s;
    lq[threadIdx.x] = q;
    __syncthreads();
    if (half == 0) {
        s += ls[threadIdx.x + 128];
        q += lq[threadIdx.x + 128];
        atomicAdd(&sums[c], s);
        atomicAdd(&sums[128 + c], q);
    }
}

__global__ void bn_finalize(const float* __restrict__ sums, const float* __restrict__ g,
                            const float* __restrict__ b, float* __restrict__ sc, int Nn)
{
    int c = threadIdx.x;  // 128 threads
    float inv = 1.f / (float)Nn;
    float mu = sums[c] * inv;
    float var = sums[128 + c] * inv - mu * mu;
    float rstd = rsqrtf(var + 1e-5f);
    float scale = rstd * g[c];
    sc[c] = scale;
    sc[128 + c] = b[c] - mu * scale;
}

__global__ __launch_bounds__(256)
void bn_apply_relu(float* __restrict__ h, const float* __restrict__ sc, size_t n4)
{
    size_t i = (size_t)blockIdx.x * 256 + threadIdx.x;
    if (i >= n4) return;
    int c = (int)(i & 31) << 2;
    float4 v = reinterpret_cast<float4*>(h)[i];
    v.x = fmaxf(fmaf(v.x, sc[c + 0], sc[128 + c + 0]), 0.f);
    v.y = fmaxf(fmaf(v.y, sc[c + 1], sc[128 + c + 1]), 0.f);
    v.z = fmaxf(fmaf(v.z, sc[c + 2], sc[128 + c + 2]), 0.f);
    v.w = fmaxf(fmaf(v.w, sc[c + 3], sc[128 + c + 3]), 0.f);
    reinterpret_cast<float4*>(h)[i] = v;
}

// ---------- degree counts (src for gcn-norm, dst for CSR) ----------
__global__ __launch_bounds__(256)
void deg_kernel(const int* __restrict__ ei, int* __restrict__ degsrc,
                int* __restrict__ cntdst, int E)
{
    int e = blockIdx.x * 256 + threadIdx.x;
    if (e < E) {
        atomicAdd(&degsrc[ei[E + e]], 1);
        atomicAdd(&cntdst[ei[e]], 1);
    }
}

__global__ __launch_bounds__(256)
void dis_kernel(const int* __restrict__ deg, float* __restrict__ dis, int Nn)
{
    int n = blockIdx.x * 256 + threadIdx.x;
    if (n < Nn) {
        int d = deg[n];
        dis[n] = d > 0 ? rsqrtf((float)d) : 0.f;
    }
}

// ---------- CSR build: 2-level exclusive scan + scatter ----------
__global__ __launch_bounds__(256)
void scan_block_sums(const int* __restrict__ cnt, int* __restrict__ bsum, int Nn)
{
    __shared__ int sd[256];
    int tid = threadIdx.x;
    int i = blockIdx.x * 256 + tid;
    sd[tid] = i < Nn ? cnt[i] : 0;
    __syncthreads();
#pragma unroll
    for (int s = 128; s > 0; s >>= 1) {
        if (tid < s) sd[tid] += sd[tid + s];
        __syncthreads();
    }
    if (tid == 0) bsum[blockIdx.x] = sd[0];
}

__global__ __launch_bounds__(1024)
void scan_offsets(int* __restrict__ bsum, int nb)   // nb <= 1024
{
    __shared__ int sd[1024];
    int tid = threadIdx.x;
    int v = tid < nb ? bsum[tid] : 0;
    sd[tid] = v;
    __syncthreads();
    for (int d = 1; d < 1024; d <<= 1) {
        int t = 0;
        if (tid >= d) t = sd[tid - d];
        __syncthreads();
        sd[tid] += t;
        __syncthreads();
    }
    if (tid < nb) bsum[tid] = sd[tid] - v;   // exclusive
}

__global__ __launch_bounds__(256)
void scan_final(const int* __restrict__ cnt, const int* __restrict__ bsum,
                int* __restrict__ rowptr, int Nn, int E)
{
    __shared__ int sd[256];
    int tid = threadIdx.x;
    int i = blockIdx.x * 256 + tid;
    int v = i < Nn ? cnt[i] : 0;
    sd[tid] = v;
    __syncthreads();
    for (int d = 1; d < 256; d <<= 1) {
        int t = 0;
        if (tid >= d) t = sd[tid - d];
        __syncthreads();
        sd[tid] += t;
        __syncthreads();
    }
    if (i < Nn) rowptr[i] = sd[tid] - v + bsum[blockIdx.x];
    if (blockIdx.x == 0 && tid == 0) rowptr[Nn] = E;
}

__global__ __launch_bounds__(256)
void scatter_csr(const int* __restrict__ ei, const int* __restrict__ et,
                 int* __restrict__ cursor, unsigned* __restrict__ csr, int E)
{
    int e = blockIdx.x * 256 + threadIdx.x;
    if (e < E) {
        int dst = ei[e];
        int src = ei[E + e];
        int pos = atomicAdd(&cursor[dst], 1);
        csr[pos] = (unsigned)src | ((unsigned)et[e] << 17);   // src < 2^17, type < 8
    }
}

// ---------- fused per-node gather: gcn-sum + scatter-softmax + combine ----------
// One wave per dst node; lane owns channels 2l, 2l+1. All feature data bf16.
__global__ __launch_bounds__(256)
void node_gather(const int* __restrict__ rowptr, const unsigned* __restrict__ csr,
                 const float* __restrict__ dis, const unsigned short* __restrict__ Xb,
                 const unsigned short* __restrict__ Y,
                 float* __restrict__ out, int Nn)
{
    int node = blockIdx.x * 4 + (threadIdx.x >> 6);
    if (node >= Nn) return;
    int lane = threadIdx.x & 63;
    int c = lane << 1;

    float dd = dis[node];
    int start = rowptr[node];
    int end = rowptr[node + 1];

    float mg0 = 0.f, mg1 = 0.f, s0 = 0.f, s1 = 0.f, t0 = 0.f, t1 = 0.f;
    for (int i = start; i < end; ++i) {
        unsigned pk = csr[i];                       // wave-uniform broadcast
        int src = (int)(pk & 0x1FFFFu);
        int r = (int)(pk >> 17);
        float nrm = dd * dis[src];
        unsigned xp = *reinterpret_cast<const unsigned*>(Xb + (size_t)src * 128 + c);
        unsigned yp = *reinterpret_cast<const unsigned*>(Y + ((size_t)r * Nn + src) * 128 + c);
        float x0 = bf2f((unsigned short)(xp & 0xffffu));
        float x1 = bf2f((unsigned short)(xp >> 16));
        float y0 = bf2f((unsigned short)(yp & 0xffffu));
        float y1 = bf2f((unsigned short)(yp >> 16));
        float w0 = __expf(y0), w1 = __expf(y1);
        mg0 = fmaf(x0, nrm, mg0);
        mg1 = fmaf(x1, nrm, mg1);
        s0 += w0; s1 += w1;
        t0 = fmaf(y0, w0, t0);
        t1 = fmaf(y1, w1, t1);
    }
    float o0 = mg0 + 0.1f * fmaxf(s0 > 0.f ? t0 / s0 : 0.f, 0.f);
    float o1 = mg1 + 0.1f * fmaxf(s1 > 0.f ? t1 / s1 : 0.f, 0.f);
    *reinterpret_cast<float2*>(out + (size_t)node * 128 + c) = make_float2(o0, o1);
}

// ---------- gather rows + exact gelu ----------
__global__ __launch_bounds__(256)
void gather_gelu(const float* __restrict__ h, const int* __restrict__ idx,
                 float* __restrict__ out, int M)
{
    int i = blockIdx.x * 256 + threadIdx.x;
    if (i >= M * 32) return;
    int row = i >> 5;
    int c = (i & 31) << 2;
    float4 v = *reinterpret_cast<const float4*>(h + (size_t)idx[row] * 128 + c);
    const float k = 0.7071067811865475f;
    v.x = 0.5f * v.x * (1.f + erff(v.x * k));
    v.y = 0.5f * v.y * (1.f + erff(v.y * k));
    v.z = 0.5f * v.z * (1.f + erff(v.z * k));
    v.w = 0.5f * v.w * (1.f + erff(v.w * k));
    reinterpret_cast<float4*>(out)[i] = v;
}

// ---------- launch ----------
extern "C" void kernel_launch(void* const* d_in, const int* in_sizes, int n_in,
                              void* d_out, int out_size, void* d_ws, size_t ws_size,
                              hipStream_t stream)
{
    const float* x      = (const float*)d_in[0];
    const int*   ei     = (const int*)d_in[1];
    const int*   et     = (const int*)d_in[2];
    // d_in[3] edge_weight: unused by the reference
    const int*   idxp   = (const int*)d_in[4];
    const float* proj_w = (const float*)d_in[5];
    const float* proj_b = (const float*)d_in[6];
    const float* bn_g   = (const float*)d_in[7];
    const float* bn_b   = (const float*)d_in[8];
    const float* win_w[2]  = {(const float*)d_in[9],  (const float*)d_in[14]};
    const float* win_b[2]  = {(const float*)d_in[10], (const float*)d_in[15]};
    const float* wrel[2]   = {(const float*)d_in[11], (const float*)d_in[16]};
    const float* cout_w[2] = {(const float*)d_in[12], (const float*)d_in[17]};
    const float* cout_b[2] = {(const float*)d_in[13], (const float*)d_in[18]};

    const int Nn  = in_sizes[0] / 128;
    const int E   = in_sizes[1] / 2;
    const int Mo  = in_sizes[4];
    const int nrel = in_sizes[11] / (128 * 128);
    const size_t ND = (size_t)Nn * 128;

    // workspace layout (~130 MB)
    char* p = (char*)d_ws;
    float* h    = (float*)p;                  p += ND * 4;
    unsigned short* Xb = (unsigned short*)p;  p += ND * 2;            // bf16 xlin
    unsigned short* Yb = (unsigned short*)p;  p += (size_t)nrel * ND * 2;
    float* msg  = (float*)p;                  p += ND * 4;
    unsigned short* Wt = (unsigned short*)p;  p += (size_t)2 * nrel * 16384 * 2;
    float* dis  = (float*)p;                  p += (size_t)Nn * 4;
    int*   deg  = (int*)p;                    p += (size_t)Nn * 4;    // over src
    int*   cnt  = (int*)p;                    p += (size_t)Nn * 4;    // over dst
    int*   rowptr = (int*)p;                  p += ((size_t)Nn + 1) * 4;
    int*   cursor = (int*)p;                  p += (size_t)Nn * 4;
    unsigned* csr = (unsigned*)p;             p += (size_t)E * 4;
    int*   bsum = (int*)p;                    p += 1024 * 4;
    float* bnsums = (float*)p;                p += 256 * 4;
    float* bnsc   = (float*)p;                p += 256 * 4;
    if ((size_t)(p - (char*)d_ws) > ws_size) return;

    const int gemmGrid = (Nn + 63) / 64;
    const size_t n4 = ND / 4;
    const int n4grid = (int)((n4 + 255) / 256);
    const int nb = (Nn + 255) / 256;

    // ---- weight prep (independent of data path) ----
    wt_convert<<<2 * nrel, 256, 0, stream>>>(wrel[0], wrel[1], Wt, nrel);

    // ---- stage 0: proj -> BN(batch stats) -> relu ----
    gemm_f32<<<gemmGrid, 256, 0, stream>>>(x, proj_w, proj_b, h, nullptr, Nn);
    hipMemsetAsync(bnsums, 0, 256 * 4, stream);
    hipMemsetAsync(deg, 0, (size_t)Nn * 4, stream);
    hipMemsetAsync(cnt, 0, (size_t)Nn * 4, stream);
    bn_stats<<<512, 256, 0, stream>>>(h, bnsums, Nn);
    bn_finalize<<<1, 128, 0, stream>>>(bnsums, bn_g, bn_b, bnsc, Nn);
    bn_apply_relu<<<n4grid, 256, 0, stream>>>(h, bnsc, n4);

    // ---- CSR build (once; shared by both layers) ----
    deg_kernel<<<(E + 255) / 256, 256, 0, stream>>>(ei, deg, cnt, E);
    dis_kernel<<<(Nn + 255) / 256, 256, 0, stream>>>(deg, dis, Nn);
    scan_block_sums<<<nb, 256, 0, stream>>>(cnt, bsum, Nn);
    scan_offsets<<<1, 1024, 0, stream>>>(bsum, nb);
    scan_final<<<nb, 256, 0, stream>>>(cnt, bsum, rowptr, Nn, E);
    hipMemcpyAsync(cursor, rowptr, (size_t)Nn * 4, hipMemcpyDeviceToDevice, stream);
    scatter_csr<<<(E + 255) / 256, 256, 0, stream>>>(ei, et, cursor, csr, E);

    // ---- two DAN layers ----
    for (int l = 0; l < 2; ++l) {
        // Xb = bf16(h @ win + b)
        gemm_f32<<<gemmGrid, 256, 0, stream>>>(h, win_w[l], win_b[l], nullptr, Xb, Nn);
        // Y[r] = Xb @ wrel[r]  (MFMA)
        gemm_mfma_y<<<dim3((Nn + 127) / 128, nrel), 256, 0, stream>>>(
            Xb, Wt + (size_t)l * nrel * 16384, Yb, Nn);
        // fused gather: gcn-sum + scatter-softmax + combine
        node_gather<<<(Nn + 3) / 4, 256, 0, stream>>>(rowptr, csr, dis, Xb, Yb, msg, Nn);
        // h = msg @ cout + b
        gemm_f32<<<gemmGrid, 256, 0, stream>>>(msg, cout_w[l], cout_b[l], h, nullptr, Nn);
    }

    gather_gelu<<<(Mo * 32 + 255) / 256, 256, 0, stream>>>(h, idxp, (float*)d_out, Mo);
}

// Round 4
// 556.669 us; speedup vs baseline: 14.4589x; 1.1916x over previous
//
#include <hip/hip_runtime.h>

// ---------- helpers ----------
__device__ inline float bf2f(unsigned short u) {
    return __uint_as_float(((unsigned)u) << 16);
}
__device__ inline unsigned short f2bf(float f) {
    unsigned u = __float_as_uint(f);
    u += 0x7fffu + ((u >> 16) & 1u);   // round-to-nearest-even
    return (unsigned short)(u >> 16);
}

typedef __attribute__((ext_vector_type(8))) short short8v;   // 8 bf16 (4 VGPRs)
typedef __attribute__((ext_vector_type(4))) float f32x4;

// ---------- f32 GEMM (proj only): C[M x 128] = A @ W + b ----------
// 64-row tile, 256 threads, thread = 4 rows x 8 cols (cols tx + 16j -> LDS
// conflict-free: 16 lanes hit 16 distinct banks, ty groups broadcast).
__global__ __launch_bounds__(256)
void gemm_f32(const float* __restrict__ A, const float* __restrict__ W,
              const float* __restrict__ bias, float* __restrict__ C, int M)
{
    __shared__ float As[64][132];
    __shared__ float Ws[32][128];

    const int tid = threadIdx.x;
    const int row0 = blockIdx.x * 64;

#pragma unroll
    for (int i = 0; i < 8; ++i) {
        int idx = tid + i * 256;
        int rr = idx >> 5;
        int cc = (idx & 31) << 2;
        int gr = row0 + rr;
        float4 v = make_float4(0.f, 0.f, 0.f, 0.f);
        if (gr < M) v = *reinterpret_cast<const float4*>(A + (size_t)gr * 128 + cc);
        *reinterpret_cast<float4*>(&As[rr][cc]) = v;
    }

    const int tx = tid & 15;
    const int ty = tid >> 4;
    float acc[4][8];
#pragma unroll
    for (int i = 0; i < 4; ++i)
#pragma unroll
        for (int j = 0; j < 8; ++j) acc[i][j] = 0.f;

    for (int kt = 0; kt < 4; ++kt) {
        __syncthreads();
#pragma unroll
        for (int i = 0; i < 4; ++i) {
            int idx = tid + i * 256;
            int rr = idx >> 5;
            int cc = (idx & 31) << 2;
            *reinterpret_cast<float4*>(&Ws[rr][cc]) =
                *reinterpret_cast<const float4*>(W + (size_t)(kt * 32 + rr) * 128 + cc);
        }
        __syncthreads();
#pragma unroll
        for (int kk = 0; kk < 32; ++kk) {
            const int k = kt * 32 + kk;
            float a0 = As[ty * 4 + 0][k];
            float a1 = As[ty * 4 + 1][k];
            float a2 = As[ty * 4 + 2][k];
            float a3 = As[ty * 4 + 3][k];
            float w[8];
#pragma unroll
            for (int j = 0; j < 8; ++j) w[j] = Ws[kk][tx + 16 * j];
#pragma unroll
            for (int j = 0; j < 8; ++j) {
                acc[0][j] = fmaf(a0, w[j], acc[0][j]);
                acc[1][j] = fmaf(a1, w[j], acc[1][j]);
                acc[2][j] = fmaf(a2, w[j], acc[2][j]);
                acc[3][j] = fmaf(a3, w[j], acc[3][j]);
            }
        }
    }

    float bb[8];
#pragma unroll
    for (int j = 0; j < 8; ++j) bb[j] = bias ? bias[tx + 16 * j] : 0.f;

#pragma unroll
    for (int i = 0; i < 4; ++i) {
        int gr = row0 + ty * 4 + i;
        if (gr >= M) continue;
#pragma unroll
        for (int j = 0; j < 8; ++j)
            C[(size_t)gr * 128 + tx + 16 * j] = acc[i][j] + bb[j];
    }
}

// ---------- weight transpose+convert: Wt[mat][n][k] bf16 <- W[mat][k][n] f32 ----------
// layout: 0:win0 1:win1 2:cout0 3:cout1 4..3+nrel:wrel0 4+nrel..:wrel1
__global__ __launch_bounds__(256)
void wt_convert(const float* __restrict__ win0, const float* __restrict__ win1,
                const float* __restrict__ cout0, const float* __restrict__ cout1,
                const float* __restrict__ wrel0, const float* __restrict__ wrel1,
                unsigned short* __restrict__ Wt, int nrel)
{
    int mat = blockIdx.x;
    const float* W;
    if (mat == 0) W = win0;
    else if (mat == 1) W = win1;
    else if (mat == 2) W = cout0;
    else if (mat == 3) W = cout1;
    else if (mat < 4 + nrel) W = wrel0 + (size_t)(mat - 4) * 16384;
    else W = wrel1 + (size_t)(mat - 4 - nrel) * 16384;
    unsigned short* O = Wt + (size_t)mat * 16384;
    for (int i = threadIdx.x; i < 16384; i += 256) {
        int k = i >> 7, n = i & 127;
        O[(size_t)n * 128 + k] = f2bf(W[i]);
    }
}

// ---------- MFMA GEMM: C = A[M x 128](bf16) @ Wt^T (+bias), f32/bf16 out ----------
// grid (ceil(M/128), nmat); 256 thr = 4 waves; wave owns 32 rows x 128 cols.
// Verified fragment mapping (in-situ round 3): A row = lane&15, k-grp = lane>>4;
// C/D: col = lane&15, row = (lane>>4)*4 + reg.
__global__ __launch_bounds__(256)
void gemm_mfma(const unsigned short* __restrict__ A,
               const unsigned short* __restrict__ Wt,
               const float* __restrict__ bias,
               float* __restrict__ Cf, unsigned short* __restrict__ Cb, int M)
{
    const int rel = blockIdx.y;
    const int wave = threadIdx.x >> 6;
    const int lane = threadIdx.x & 63;
    const int row0 = blockIdx.x * 128 + wave * 32;
    const int grp = lane >> 4;
    const int l16 = lane & 15;

    const unsigned short* Wr = Wt + (size_t)rel * 16384;
    f32x4 acc[2][8] = {};

#pragma unroll
    for (int kt = 0; kt < 4; ++kt) {
        const int k0 = kt * 32 + grp * 8;
        short8v a[2];
#pragma unroll
        for (int m = 0; m < 2; ++m) {
            int r = row0 + 16 * m + l16;
            if (r > M - 1) r = M - 1;          // clamp; tail rows not stored
            a[m] = *reinterpret_cast<const short8v*>(A + (size_t)r * 128 + k0);
        }
#pragma unroll
        for (int n = 0; n < 8; ++n) {
            short8v b = *reinterpret_cast<const short8v*>(Wr + (size_t)(16 * n + l16) * 128 + k0);
            acc[0][n] = __builtin_amdgcn_mfma_f32_16x16x32_bf16(a[0], b, acc[0][n], 0, 0, 0);
            acc[1][n] = __builtin_amdgcn_mfma_f32_16x16x32_bf16(a[1], b, acc[1][n], 0, 0, 0);
        }
    }

    float bb[8];
#pragma unroll
    for (int n = 0; n < 8; ++n) bb[n] = bias ? bias[16 * n + l16] : 0.f;

    float* Cfr = Cf ? Cf + (size_t)rel * (size_t)M * 128 : nullptr;
    unsigned short* Cbr = Cb ? Cb + (size_t)rel * (size_t)M * 128 : nullptr;

#pragma unroll
    for (int m = 0; m < 2; ++m)
#pragma unroll
        for (int n = 0; n < 8; ++n)
#pragma unroll
            for (int r = 0; r < 4; ++r) {
                int row = row0 + 16 * m + grp * 4 + r;
                if (row < M) {
                    float v = acc[m][n][r] + bb[n];
                    if (Cfr) Cfr[(size_t)row * 128 + 16 * n + l16] = v;
                    if (Cbr) Cbr[(size_t)row * 128 + 16 * n + l16] = f2bf(v);
                }
            }
}

// ---------- BatchNorm (training-mode batch stats) ----------
__global__ __launch_bounds__(256)
void bn_stats(const float* __restrict__ h, float* __restrict__ sums, int Nn)
{
    const int c = threadIdx.x & 127;
    const int half = threadIdx.x >> 7;
    float s = 0.f, q = 0.f;
    for (int row = blockIdx.x * 2 + half; row < Nn; row += gridDim.x * 2) {
        float v = h[(size_t)row * 128 + c];
        s += v;
        q += v * v;
    }
    __shared__ float ls[256], lq[256];
    ls[threadIdx.x] = s;
    lq[threadIdx.x] = q;
    __syncthreads();
    if (half == 0) {
        s += ls[threadIdx.x + 128];
        q += lq[threadIdx.x + 128];
        atomicAdd(&sums[c], s);
        atomicAdd(&sums[128 + c], q);
    }
}

__global__ void bn_finalize(const float* __restrict__ sums, const float* __restrict__ g,
                            const float* __restrict__ b, float* __restrict__ sc, int Nn)
{
    int c = threadIdx.x;  // 128 threads
    float inv = 1.f / (float)Nn;
    float mu = sums[c] * inv;
    float var = sums[128 + c] * inv - mu * mu;
    float rstd = rsqrtf(var + 1e-5f);
    float scale = rstd * g[c];
    sc[c] = scale;
    sc[128 + c] = b[c] - mu * scale;
}

// h f32 -> hb bf16 with BN + relu (h itself no longer needed afterwards)
__global__ __launch_bounds__(256)
void bn_apply_relu(const float* __restrict__ h, const float* __restrict__ sc,
                   unsigned short* __restrict__ hb, size_t n4)
{
    size_t i = (size_t)blockIdx.x * 256 + threadIdx.x;
    if (i >= n4) return;
    int c = (int)(i & 31) << 2;
    float4 v = reinterpret_cast<const float4*>(h)[i];
    float o0 = fmaxf(fmaf(v.x, sc[c + 0], sc[128 + c + 0]), 0.f);
    float o1 = fmaxf(fmaf(v.y, sc[c + 1], sc[128 + c + 1]), 0.f);
    float o2 = fmaxf(fmaf(v.z, sc[c + 2], sc[128 + c + 2]), 0.f);
    float o3 = fmaxf(fmaf(v.w, sc[c + 3], sc[128 + c + 3]), 0.f);
    ushort4 pk = make_ushort4(f2bf(o0), f2bf(o1), f2bf(o2), f2bf(o3));
    reinterpret_cast<ushort4*>(hb)[i] = pk;
}

// ---------- degree counts (src for gcn-norm, dst for CSR) ----------
__global__ __launch_bounds__(256)
void deg_kernel(const int* __restrict__ ei, int* __restrict__ degsrc,
                int* __restrict__ cntdst, int E)
{
    int e = blockIdx.x * 256 + threadIdx.x;
    if (e < E) {
        atomicAdd(&degsrc[ei[E + e]], 1);
        atomicAdd(&cntdst[ei[e]], 1);
    }
}

__global__ __launch_bounds__(256)
void dis_kernel(const int* __restrict__ deg, float* __restrict__ dis, int Nn)
{
    int n = blockIdx.x * 256 + threadIdx.x;
    if (n < Nn) {
        int d = deg[n];
        dis[n] = d > 0 ? rsqrtf((float)d) : 0.f;
    }
}

// ---------- CSR build: 2-level exclusive scan + scatter ----------
__global__ __launch_bounds__(256)
void scan_block_sums(const int* __restrict__ cnt, int* __restrict__ bsum, int Nn)
{
    __shared__ int sd[256];
    int tid = threadIdx.x;
    int i = blockIdx.x * 256 + tid;
    sd[tid] = i < Nn ? cnt[i] : 0;
    __syncthreads();
#pragma unroll
    for (int s = 128; s > 0; s >>= 1) {
        if (tid < s) sd[tid] += sd[tid + s];
        __syncthreads();
    }
    if (tid == 0) bsum[blockIdx.x] = sd[0];
}

__global__ __launch_bounds__(1024)
void scan_offsets(int* __restrict__ bsum, int nb)   // nb <= 1024
{
    __shared__ int sd[1024];
    int tid = threadIdx.x;
    int v = tid < nb ? bsum[tid] : 0;
    sd[tid] = v;
    __syncthreads();
    for (int d = 1; d < 1024; d <<= 1) {
        int t = 0;
        if (tid >= d) t = sd[tid - d];
        __syncthreads();
        sd[tid] += t;
        __syncthreads();
    }
    if (tid < nb) bsum[tid] = sd[tid] - v;   // exclusive
}

__global__ __launch_bounds__(256)
void scan_final(const int* __restrict__ cnt, const int* __restrict__ bsum,
                int* __restrict__ rowptr, int* __restrict__ cursor, int Nn, int E)
{
    __shared__ int sd[256];
    int tid = threadIdx.x;
    int i = blockIdx.x * 256 + tid;
    int v = i < Nn ? cnt[i] : 0;
    sd[tid] = v;
    __syncthreads();
    for (int d = 1; d < 256; d <<= 1) {
        int t = 0;
        if (tid >= d) t = sd[tid - d];
        __syncthreads();
        sd[tid] += t;
        __syncthreads();
    }
    if (i < Nn) {
        int off = sd[tid] - v + bsum[blockIdx.x];
        rowptr[i] = off;
        cursor[i] = off;
    }
    if (blockIdx.x == 0 && tid == 0) rowptr[Nn] = E;
}

__global__ __launch_bounds__(256)
void scatter_csr(const int* __restrict__ ei, const int* __restrict__ et,
                 const float* __restrict__ dis, int* __restrict__ cursor,
                 uint2* __restrict__ csr, int E)
{
    int e = blockIdx.x * 256 + threadIdx.x;
    if (e < E) {
        int dst = ei[e];
        int src = ei[E + e];
        int pos = atomicAdd(&cursor[dst], 1);
        float nrm = dis[dst] * dis[src];
        csr[pos] = make_uint2((unsigned)src | ((unsigned)et[e] << 17),
                              __float_as_uint(nrm));
    }
}

// ---------- fused per-node gather: gcn-sum + scatter-softmax + combine ----------
// One wave per dst node; lane owns channels 2l, 2l+1. Edge loop unrolled x4:
// 8 independent gathers in flight per step (latency hiding). bf16 output.
__global__ __launch_bounds__(256)
void node_gather(const int* __restrict__ rowptr, const uint2* __restrict__ csr,
                 const unsigned short* __restrict__ Xb,
                 const unsigned short* __restrict__ Y,
                 unsigned short* __restrict__ outb, int Nn)
{
    int node = blockIdx.x * 4 + (threadIdx.x >> 6);
    if (node >= Nn) return;
    int lane = threadIdx.x & 63;
    int c = lane << 1;

    int i = rowptr[node];
    const int end = rowptr[node + 1];

    float mg0 = 0.f, mg1 = 0.f, s0 = 0.f, s1 = 0.f, t0 = 0.f, t1 = 0.f;

    for (; i + 4 <= end; i += 4) {
        uint2 e0 = csr[i], e1 = csr[i + 1], e2 = csr[i + 2], e3 = csr[i + 3];
        unsigned xp[4], yp[4];
        {
            size_t s_ = e0.x & 0x1FFFFu, r_ = e0.x >> 17;
            xp[0] = *reinterpret_cast<const unsigned*>(Xb + s_ * 128 + c);
            yp[0] = *reinterpret_cast<const unsigned*>(Y + (r_ * Nn + s_) * 128 + c);
        }
        {
            size_t s_ = e1.x & 0x1FFFFu, r_ = e1.x >> 17;
            xp[1] = *reinterpret_cast<const unsigned*>(Xb + s_ * 128 + c);
            yp[1] = *reinterpret_cast<const unsigned*>(Y + (r_ * Nn + s_) * 128 + c);
        }
        {
            size_t s_ = e2.x & 0x1FFFFu, r_ = e2.x >> 17;
            xp[2] = *reinterpret_cast<const unsigned*>(Xb + s_ * 128 + c);
            yp[2] = *reinterpret_cast<const unsigned*>(Y + (r_ * Nn + s_) * 128 + c);
        }
        {
            size_t s_ = e3.x & 0x1FFFFu, r_ = e3.x >> 17;
            xp[3] = *reinterpret_cast<const unsigned*>(Xb + s_ * 128 + c);
            yp[3] = *reinterpret_cast<const unsigned*>(Y + (r_ * Nn + s_) * 128 + c);
        }
        unsigned nr[4] = {e0.y, e1.y, e2.y, e3.y};
#pragma unroll
        for (int q = 0; q < 4; ++q) {
            float nrm = __uint_as_float(nr[q]);
            float x0 = bf2f((unsigned short)(xp[q] & 0xffffu));
            float x1 = bf2f((unsigned short)(xp[q] >> 16));
            float y0 = bf2f((unsigned short)(yp[q] & 0xffffu));
            float y1 = bf2f((unsigned short)(yp[q] >> 16));
            float w0 = __expf(y0), w1 = __expf(y1);
            mg0 = fmaf(x0, nrm, mg0);
            mg1 = fmaf(x1, nrm, mg1);
            s0 += w0; s1 += w1;
            t0 = fmaf(y0, w0, t0);
            t1 = fmaf(y1, w1, t1);
        }
    }
    for (; i < end; ++i) {
        uint2 e0 = csr[i];
        size_t s_ = e0.x & 0x1FFFFu, r_ = e0.x >> 17;
        float nrm = __uint_as_float(e0.y);
        unsigned xp = *reinterpret_cast<const unsigned*>(Xb + s_ * 128 + c);
        unsigned yp = *reinterpret_cast<const unsigned*>(Y + (r_ * Nn + s_) * 128 + c);
        float x0 = bf2f((unsigned short)(xp & 0xffffu));
        float x1 = bf2f((unsigned short)(xp >> 16));
        float y0 = bf2f((unsigned short)(yp & 0xffffu));
        float y1 = bf2f((unsigned short)(yp >> 16));
        float w0 = __expf(y0), w1 = __expf(y1);
        mg0 = fmaf(x0, nrm, mg0);
        mg1 = fmaf(x1, nrm, mg1);
        s0 += w0; s1 += w1;
        t0 = fmaf(y0, w0, t0);
        t1 = fmaf(y1, w1, t1);
    }

    float o0 = mg0 + 0.1f * fmaxf(s0 > 0.f ? t0 / s0 : 0.f, 0.f);
    float o1 = mg1 + 0.1f * fmaxf(s1 > 0.f ? t1 / s1 : 0.f, 0.f);
    unsigned pk = (unsigned)f2bf(o0) | ((unsigned)f2bf(o1) << 16);
    *reinterpret_cast<unsigned*>(outb + (size_t)node * 128 + c) = pk;
}

// ---------- gather rows + exact gelu ----------
__global__ __launch_bounds__(256)
void gather_gelu(const float* __restrict__ h, const int* __restrict__ idx,
                 float* __restrict__ out, int M)
{
    int i = blockIdx.x * 256 + threadIdx.x;
    if (i >= M * 32) return;
    int row = i >> 5;
    int c = (i & 31) << 2;
    float4 v = *reinterpret_cast<const float4*>(h + (size_t)idx[row] * 128 + c);
    const float k = 0.7071067811865475f;
    v.x = 0.5f * v.x * (1.f + erff(v.x * k));
    v.y = 0.5f * v.y * (1.f + erff(v.y * k));
    v.z = 0.5f * v.z * (1.f + erff(v.z * k));
    v.w = 0.5f * v.w * (1.f + erff(v.w * k));
    reinterpret_cast<float4*>(out)[i] = v;
}

// ---------- launch ----------
extern "C" void kernel_launch(void* const* d_in, const int* in_sizes, int n_in,
                              void* d_out, int out_size, void* d_ws, size_t ws_size,
                              hipStream_t stream)
{
    const float* x      = (const float*)d_in[0];
    const int*   ei     = (const int*)d_in[1];
    const int*   et     = (const int*)d_in[2];
    // d_in[3] edge_weight: unused by the reference
    const int*   idxp   = (const int*)d_in[4];
    const float* proj_w = (const float*)d_in[5];
    const float* proj_b = (const float*)d_in[6];
    const float* bn_g   = (const float*)d_in[7];
    const float* bn_b   = (const float*)d_in[8];
    const float* win_w[2]  = {(const float*)d_in[9],  (const float*)d_in[14]};
    const float* win_b[2]  = {(const float*)d_in[10], (const float*)d_in[15]};
    const float* wrel[2]   = {(const float*)d_in[11], (const float*)d_in[16]};
    const float* cout_w[2] = {(const float*)d_in[12], (const float*)d_in[17]};
    const float* cout_b[2] = {(const float*)d_in[13], (const float*)d_in[18]};

    const int Nn  = in_sizes[0] / 128;
    const int E   = in_sizes[1] / 2;
    const int Mo  = in_sizes[4];
    const int nrel = in_sizes[11] / (128 * 128);
    const size_t ND = (size_t)Nn * 128;

    // workspace layout
    char* p = (char*)d_ws;
    float* h    = (float*)p;                  p += ND * 4;            // proj out / final out
    unsigned short* hb = (unsigned short*)p;  p += ND * 2;            // bf16 h (layer input)
    unsigned short* Xb = (unsigned short*)p;  p += ND * 2;            // bf16 xlin
    unsigned short* Yb = (unsigned short*)p;  p += (size_t)nrel * ND * 2;
    unsigned short* msgb = (unsigned short*)p; p += ND * 2;           // bf16 msg
    unsigned short* Wt = (unsigned short*)p;  p += (size_t)(4 + 2 * nrel) * 16384 * 2;
    uint2* csr  = (uint2*)p;                  p += (size_t)E * 8;
    float* dis  = (float*)p;                  p += (size_t)Nn * 4;
    int*   deg  = (int*)p;                    p += (size_t)Nn * 4;    // over src
    int*   cnt  = (int*)p;                    p += (size_t)Nn * 4;    // over dst (adjacent to deg)
    int*   rowptr = (int*)p;                  p += ((size_t)Nn + 1) * 4;
    int*   cursor = (int*)p;                  p += (size_t)Nn * 4;
    int*   bsum = (int*)p;                    p += 1024 * 4;
    float* bnsums = (float*)p;                p += 256 * 4;
    float* bnsc   = (float*)p;                p += 256 * 4;
    if ((size_t)(p - (char*)d_ws) > ws_size) return;

    const int WIN0 = 0, WIN1 = 1, COUT0 = 2, COUT1 = 3, WREL0 = 4;
    const int WREL1 = 4 + nrel;

    const int gemmGrid = (Nn + 63) / 64;
    const int mfmaGrid = (Nn + 127) / 128;
    const size_t n4 = ND / 4;
    const int n4grid = (int)((n4 + 255) / 256);
    const int nb = (Nn + 255) / 256;

    // ---- weight prep (independent of data path) ----
    wt_convert<<<4 + 2 * nrel, 256, 0, stream>>>(win_w[0], win_w[1], cout_w[0], cout_w[1],
                                                 wrel[0], wrel[1], Wt, nrel);

    // ---- stage 0: proj -> BN(batch stats) -> relu -> hb (bf16) ----
    gemm_f32<<<gemmGrid, 256, 0, stream>>>(x, proj_w, proj_b, h, Nn);
    hipMemsetAsync(bnsums, 0, 256 * 4, stream);
    hipMemsetAsync(deg, 0, (size_t)Nn * 8, stream);   // deg + cnt (adjacent)
    bn_stats<<<512, 256, 0, stream>>>(h, bnsums, Nn);
    bn_finalize<<<1, 128, 0, stream>>>(bnsums, bn_g, bn_b, bnsc, Nn);
    bn_apply_relu<<<n4grid, 256, 0, stream>>>(h, bnsc, hb, n4);

    // ---- CSR build (once; shared by both layers) ----
    deg_kernel<<<(E + 255) / 256, 256, 0, stream>>>(ei, deg, cnt, E);
    dis_kernel<<<(Nn + 255) / 256, 256, 0, stream>>>(deg, dis, Nn);
    scan_block_sums<<<nb, 256, 0, stream>>>(cnt, bsum, Nn);
    scan_offsets<<<1, 1024, 0, stream>>>(bsum, nb);
    scan_final<<<nb, 256, 0, stream>>>(cnt, bsum, rowptr, cursor, Nn, E);
    scatter_csr<<<(E + 255) / 256, 256, 0, stream>>>(ei, et, dis, cursor, csr, E);

    // ---- two DAN layers (all GEMMs via MFMA) ----
    for (int l = 0; l < 2; ++l) {
        // Xb = bf16(hb @ win + b)
        gemm_mfma<<<dim3(mfmaGrid, 1), 256, 0, stream>>>(
            hb, Wt + (size_t)(l == 0 ? WIN0 : WIN1) * 16384, win_b[l], nullptr, Xb, Nn);
        // Y[r] = Xb @ wrel[r]
        gemm_mfma<<<dim3(mfmaGrid, nrel), 256, 0, stream>>>(
            Xb, Wt + (size_t)(l == 0 ? WREL0 : WREL1) * 16384, nullptr, nullptr, Yb, Nn);
        // fused gather: gcn-sum + scatter-softmax + combine -> msgb (bf16)
        node_gather<<<(Nn + 3) / 4, 256, 0, stream>>>(rowptr, csr, Xb, Yb, msgb, Nn);
        // h(b) = msgb @ cout + b ; layer0 -> bf16 hb, layer1 -> f32 h
        if (l == 0)
            gemm_mfma<<<dim3(mfmaGrid, 1), 256, 0, stream>>>(
                msgb, Wt + (size_t)COUT0 * 16384, cout_b[0], nullptr, hb, Nn);
        else
            gemm_mfma<<<dim3(mfmaGrid, 1), 256, 0, stream>>>(
                msgb, Wt + (size_t)COUT1 * 16384, cout_b[1], h, nullptr, Nn);
    }

    gather_gelu<<<(Mo * 32 + 255) / 256, 256, 0, stream>>>(h, idxp, (float*)d_out, Mo);
}

// Round 5
// 506.846 us; speedup vs baseline: 15.8803x; 1.0983x over previous
//
#include <hip/hip_runtime.h>

// ---------- helpers ----------
__device__ inline float bf2f(unsigned short u) {
    return __uint_as_float(((unsigned)u) << 16);
}
__device__ inline unsigned short f2bf(float f) {
    unsigned u = __float_as_uint(f);
    u += 0x7fffu + ((u >> 16) & 1u);   // round-to-nearest-even
    return (unsigned short)(u >> 16);
}

typedef __attribute__((ext_vector_type(8))) short short8v;   // 8 bf16 (4 VGPRs)
typedef __attribute__((ext_vector_type(4))) float f32x4;

// ---------- f32 GEMM (proj only): C[M x 128] = A @ W + b ----------
// 64-row tile, 256 threads, thread = 4 rows x 8 cols (cols tx + 16j -> LDS
// conflict-free: 16 lanes hit 16 distinct banks, ty groups broadcast).
__global__ __launch_bounds__(256)
void gemm_f32(const float* __restrict__ A, const float* __restrict__ W,
              const float* __restrict__ bias, float* __restrict__ C, int M)
{
    __shared__ float As[64][132];
    __shared__ float Ws[32][128];

    const int tid = threadIdx.x;
    const int row0 = blockIdx.x * 64;

#pragma unroll
    for (int i = 0; i < 8; ++i) {
        int idx = tid + i * 256;
        int rr = idx >> 5;
        int cc = (idx & 31) << 2;
        int gr = row0 + rr;
        float4 v = make_float4(0.f, 0.f, 0.f, 0.f);
        if (gr < M) v = *reinterpret_cast<const float4*>(A + (size_t)gr * 128 + cc);
        *reinterpret_cast<float4*>(&As[rr][cc]) = v;
    }

    const int tx = tid & 15;
    const int ty = tid >> 4;
    float acc[4][8];
#pragma unroll
    for (int i = 0; i < 4; ++i)
#pragma unroll
        for (int j = 0; j < 8; ++j) acc[i][j] = 0.f;

    for (int kt = 0; kt < 4; ++kt) {
        __syncthreads();
#pragma unroll
        for (int i = 0; i < 4; ++i) {
            int idx = tid + i * 256;
            int rr = idx >> 5;
            int cc = (idx & 31) << 2;
            *reinterpret_cast<float4*>(&Ws[rr][cc]) =
                *reinterpret_cast<const float4*>(W + (size_t)(kt * 32 + rr) * 128 + cc);
        }
        __syncthreads();
#pragma unroll
        for (int kk = 0; kk < 32; ++kk) {
            const int k = kt * 32 + kk;
            float a0 = As[ty * 4 + 0][k];
            float a1 = As[ty * 4 + 1][k];
            float a2 = As[ty * 4 + 2][k];
            float a3 = As[ty * 4 + 3][k];
            float w[8];
#pragma unroll
            for (int j = 0; j < 8; ++j) w[j] = Ws[kk][tx + 16 * j];
#pragma unroll
            for (int j = 0; j < 8; ++j) {
                acc[0][j] = fmaf(a0, w[j], acc[0][j]);
                acc[1][j] = fmaf(a1, w[j], acc[1][j]);
                acc[2][j] = fmaf(a2, w[j], acc[2][j]);
                acc[3][j] = fmaf(a3, w[j], acc[3][j]);
            }
        }
    }

    float bb[8];
#pragma unroll
    for (int j = 0; j < 8; ++j) bb[j] = bias ? bias[tx + 16 * j] : 0.f;

#pragma unroll
    for (int i = 0; i < 4; ++i) {
        int gr = row0 + ty * 4 + i;
        if (gr >= M) continue;
#pragma unroll
        for (int j = 0; j < 8; ++j)
            C[(size_t)gr * 128 + tx + 16 * j] = acc[i][j] + bb[j];
    }
}

// ---------- weight transpose+convert: Wt[mat][n][k] bf16 <- W[mat][k][n] f32 ----------
// layout: 0:win0 1:win1 2:cout0 3:cout1 4..3+nrel:wrel0 4+nrel..:wrel1
__global__ __launch_bounds__(256)
void wt_convert(const float* __restrict__ win0, const float* __restrict__ win1,
                const float* __restrict__ cout0, const float* __restrict__ cout1,
                const float* __restrict__ wrel0, const float* __restrict__ wrel1,
                unsigned short* __restrict__ Wt, int nrel)
{
    int mat = blockIdx.x;
    const float* W;
    if (mat == 0) W = win0;
    else if (mat == 1) W = win1;
    else if (mat == 2) W = cout0;
    else if (mat == 3) W = cout1;
    else if (mat < 4 + nrel) W = wrel0 + (size_t)(mat - 4) * 16384;
    else W = wrel1 + (size_t)(mat - 4 - nrel) * 16384;
    unsigned short* O = Wt + (size_t)mat * 16384;
    for (int i = threadIdx.x; i < 16384; i += 256) {
        int k = i >> 7, n = i & 127;
        O[(size_t)n * 128 + k] = f2bf(W[i]);
    }
}

// ---------- MFMA GEMM: C = A[M x 128](bf16) @ Wt^T (+bias), f32/bf16 out ----------
// grid (ceil(M/128), nmat); 256 thr = 4 waves; wave owns 32 rows x 128 cols.
// OPERAND-SWAPPED: D = mfma(Wt_frag, X_frag) so D col (lane&15) = X-row and
// D row (grp*4+reg) = channel -> each lane's 4 regs are 4 CONSECUTIVE output
// channels of one row: pack to one 8B (bf16) / 16B (f32) store per (m,n).
__global__ __launch_bounds__(256)
void gemm_mfma(const unsigned short* __restrict__ A,
               const unsigned short* __restrict__ Wt,
               const float* __restrict__ bias,
               float* __restrict__ Cf, unsigned short* __restrict__ Cb, int M)
{
    const int rel = blockIdx.y;
    const int wave = threadIdx.x >> 6;
    const int lane = threadIdx.x & 63;
    const int row0 = blockIdx.x * 128 + wave * 32;
    const int grp = lane >> 4;
    const int l16 = lane & 15;

    const unsigned short* Wr = Wt + (size_t)rel * 16384;
    f32x4 acc[2][8] = {};

#pragma unroll
    for (int kt = 0; kt < 4; ++kt) {
        const int k0 = kt * 32 + grp * 8;
        short8v a[2];
#pragma unroll
        for (int m = 0; m < 2; ++m) {
            int r = row0 + 16 * m + l16;
            if (r > M - 1) r = M - 1;          // clamp; tail rows not stored
            a[m] = *reinterpret_cast<const short8v*>(A + (size_t)r * 128 + k0);
        }
#pragma unroll
        for (int n = 0; n < 8; ++n) {
            short8v b = *reinterpret_cast<const short8v*>(Wr + (size_t)(16 * n + l16) * 128 + k0);
            // swapped: D[chan][xrow]
            acc[0][n] = __builtin_amdgcn_mfma_f32_16x16x32_bf16(b, a[0], acc[0][n], 0, 0, 0);
            acc[1][n] = __builtin_amdgcn_mfma_f32_16x16x32_bf16(b, a[1], acc[1][n], 0, 0, 0);
        }
    }

    // bias for channels 16n + grp*4 + {0..3}
    float4 bb[8];
#pragma unroll
    for (int n = 0; n < 8; ++n)
        bb[n] = bias ? *reinterpret_cast<const float4*>(bias + 16 * n + grp * 4)
                     : make_float4(0.f, 0.f, 0.f, 0.f);

    float* Cfr = Cf ? Cf + (size_t)rel * (size_t)M * 128 : nullptr;
    unsigned short* Cbr = Cb ? Cb + (size_t)rel * (size_t)M * 128 : nullptr;

#pragma unroll
    for (int m = 0; m < 2; ++m) {
        int row = row0 + 16 * m + l16;
        if (row >= M) continue;
#pragma unroll
        for (int n = 0; n < 8; ++n) {
            float v0 = acc[m][n][0] + bb[n].x;
            float v1 = acc[m][n][1] + bb[n].y;
            float v2 = acc[m][n][2] + bb[n].z;
            float v3 = acc[m][n][3] + bb[n].w;
            if (Cfr) {
                *reinterpret_cast<float4*>(Cfr + (size_t)row * 128 + 16 * n + grp * 4) =
                    make_float4(v0, v1, v2, v3);
            }
            if (Cbr) {
                unsigned u0 = (unsigned)f2bf(v0) | ((unsigned)f2bf(v1) << 16);
                unsigned u1 = (unsigned)f2bf(v2) | ((unsigned)f2bf(v3) << 16);
                *reinterpret_cast<uint2*>(Cbr + (size_t)row * 128 + 16 * n + grp * 4) =
                    make_uint2(u0, u1);
            }
        }
    }
}

// ---------- BatchNorm (training-mode batch stats) ----------
__global__ __launch_bounds__(256)
void bn_stats(const float* __restrict__ h, float* __restrict__ sums, int Nn)
{
    const int c = threadIdx.x & 127;
    const int half = threadIdx.x >> 7;
    float s = 0.f, q = 0.f;
    for (int row = blockIdx.x * 2 + half; row < Nn; row += gridDim.x * 2) {
        float v = h[(size_t)row * 128 + c];
        s += v;
        q += v * v;
    }
    __shared__ float ls[256], lq[256];
    ls[threadIdx.x] = s;
    lq[threadIdx.x] = q;
    __syncthreads();
    if (half == 0) {
        s += ls[threadIdx.x + 128];
        q += lq[threadIdx.x + 128];
        atomicAdd(&sums[c], s);
        atomicAdd(&sums[128 + c], q);
    }
}

__global__ void bn_finalize(const float* __restrict__ sums, const float* __restrict__ g,
                            const float* __restrict__ b, float* __restrict__ sc, int Nn)
{
    int c = threadIdx.x;  // 128 threads
    float inv = 1.f / (float)Nn;
    float mu = sums[c] * inv;
    float var = sums[128 + c] * inv - mu * mu;
    float rstd = rsqrtf(var + 1e-5f);
    float scale = rstd * g[c];
    sc[c] = scale;
    sc[128 + c] = b[c] - mu * scale;
}

// h f32 -> hb bf16 with BN + relu
__global__ __launch_bounds__(256)
void bn_apply_relu(const float* __restrict__ h, const float* __restrict__ sc,
                   unsigned short* __restrict__ hb, size_t n4)
{
    size_t i = (size_t)blockIdx.x * 256 + threadIdx.x;
    if (i >= n4) return;
    int c = (int)(i & 31) << 2;
    float4 v = reinterpret_cast<const float4*>(h)[i];
    float o0 = fmaxf(fmaf(v.x, sc[c + 0], sc[128 + c + 0]), 0.f);
    float o1 = fmaxf(fmaf(v.y, sc[c + 1], sc[128 + c + 1]), 0.f);
    float o2 = fmaxf(fmaf(v.z, sc[c + 2], sc[128 + c + 2]), 0.f);
    float o3 = fmaxf(fmaf(v.w, sc[c + 3], sc[128 + c + 3]), 0.f);
    ushort4 pk = make_ushort4(f2bf(o0), f2bf(o1), f2bf(o2), f2bf(o3));
    reinterpret_cast<ushort4*>(hb)[i] = pk;
}

// ---------- degree counts (src for gcn-norm, dst for CSR) ----------
__global__ __launch_bounds__(256)
void deg_kernel(const int* __restrict__ ei, int* __restrict__ degsrc,
                int* __restrict__ cntdst, int E)
{
    int e = blockIdx.x * 256 + threadIdx.x;
    if (e < E) {
        atomicAdd(&degsrc[ei[E + e]], 1);
        atomicAdd(&cntdst[ei[e]], 1);
    }
}

__global__ __launch_bounds__(256)
void dis_kernel(const int* __restrict__ deg, float* __restrict__ dis, int Nn)
{
    int n = blockIdx.x * 256 + threadIdx.x;
    if (n < Nn) {
        int d = deg[n];
        dis[n] = d > 0 ? rsqrtf((float)d) : 0.f;
    }
}

// ---------- CSR build: 2-level exclusive scan + scatter ----------
__global__ __launch_bounds__(256)
void scan_block_sums(const int* __restrict__ cnt, int* __restrict__ bsum, int Nn)
{
    __shared__ int sd[256];
    int tid = threadIdx.x;
    int i = blockIdx.x * 256 + tid;
    sd[tid] = i < Nn ? cnt[i] : 0;
    __syncthreads();
#pragma unroll
    for (int s = 128; s > 0; s >>= 1) {
        if (tid < s) sd[tid] += sd[tid + s];
        __syncthreads();
    }
    if (tid == 0) bsum[blockIdx.x] = sd[0];
}

__global__ __launch_bounds__(1024)
void scan_offsets(int* __restrict__ bsum, int nb)   // nb <= 1024
{
    __shared__ int sd[1024];
    int tid = threadIdx.x;
    int v = tid < nb ? bsum[tid] : 0;
    sd[tid] = v;
    __syncthreads();
    for (int d = 1; d < 1024; d <<= 1) {
        int t = 0;
        if (tid >= d) t = sd[tid - d];
        __syncthreads();
        sd[tid] += t;
        __syncthreads();
    }
    if (tid < nb) bsum[tid] = sd[tid] - v;   // exclusive
}

__global__ __launch_bounds__(256)
void scan_final(const int* __restrict__ cnt, const int* __restrict__ bsum,
                int* __restrict__ rowptr, int* __restrict__ cursor, int Nn, int E)
{
    __shared__ int sd[256];
    int tid = threadIdx.x;
    int i = blockIdx.x * 256 + tid;
    int v = i < Nn ? cnt[i] : 0;
    sd[tid] = v;
    __syncthreads();
    for (int d = 1; d < 256; d <<= 1) {
        int t = 0;
        if (tid >= d) t = sd[tid - d];
        __syncthreads();
        sd[tid] += t;
        __syncthreads();
    }
    if (i < Nn) {
        int off = sd[tid] - v + bsum[blockIdx.x];
        rowptr[i] = off;
        cursor[i] = off;
    }
    if (blockIdx.x == 0 && tid == 0) rowptr[Nn] = E;
}

__global__ __launch_bounds__(256)
void scatter_csr(const int* __restrict__ ei, const int* __restrict__ et,
                 const float* __restrict__ dis, int* __restrict__ cursor,
                 uint2* __restrict__ csr, int E)
{
    int e = blockIdx.x * 256 + threadIdx.x;
    if (e < E) {
        int dst = ei[e];
        int src = ei[E + e];
        int pos = atomicAdd(&cursor[dst], 1);
        float nrm = dis[dst] * dis[src];
        csr[pos] = make_uint2((unsigned)src | ((unsigned)et[e] << 17),
                              __float_as_uint(nrm));
    }
}

// ---------- fused per-node gather: gcn-sum + scatter-softmax + combine ----------
// One wave per dst node; lane owns channels 2l, 2l+1. Edge loop unrolled x4:
// 8 independent gathers in flight per step (latency hiding). bf16 output.
__global__ __launch_bounds__(256)
void node_gather(const int* __restrict__ rowptr, const uint2* __restrict__ csr,
                 const unsigned short* __restrict__ Xb,
                 const unsigned short* __restrict__ Y,
                 unsigned short* __restrict__ outb, int Nn)
{
    int node = blockIdx.x * 4 + (threadIdx.x >> 6);
    if (node >= Nn) return;
    int lane = threadIdx.x & 63;
    int c = lane << 1;

    int i = rowptr[node];
    const int end = rowptr[node + 1];

    float mg0 = 0.f, mg1 = 0.f, s0 = 0.f, s1 = 0.f, t0 = 0.f, t1 = 0.f;

    for (; i + 4 <= end; i += 4) {
        uint2 e0 = csr[i], e1 = csr[i + 1], e2 = csr[i + 2], e3 = csr[i + 3];
        unsigned xp[4], yp[4];
        {
            size_t s_ = e0.x & 0x1FFFFu, r_ = e0.x >> 17;
            xp[0] = *reinterpret_cast<const unsigned*>(Xb + s_ * 128 + c);
            yp[0] = *reinterpret_cast<const unsigned*>(Y + (r_ * Nn + s_) * 128 + c);
        }
        {
            size_t s_ = e1.x & 0x1FFFFu, r_ = e1.x >> 17;
            xp[1] = *reinterpret_cast<const unsigned*>(Xb + s_ * 128 + c);
            yp[1] = *reinterpret_cast<const unsigned*>(Y + (r_ * Nn + s_) * 128 + c);
        }
        {
            size_t s_ = e2.x & 0x1FFFFu, r_ = e2.x >> 17;
            xp[2] = *reinterpret_cast<const unsigned*>(Xb + s_ * 128 + c);
            yp[2] = *reinterpret_cast<const unsigned*>(Y + (r_ * Nn + s_) * 128 + c);
        }
        {
            size_t s_ = e3.x & 0x1FFFFu, r_ = e3.x >> 17;
            xp[3] = *reinterpret_cast<const unsigned*>(Xb + s_ * 128 + c);
            yp[3] = *reinterpret_cast<const unsigned*>(Y + (r_ * Nn + s_) * 128 + c);
        }
        unsigned nr[4] = {e0.y, e1.y, e2.y, e3.y};
#pragma unroll
        for (int q = 0; q < 4; ++q) {
            float nrm = __uint_as_float(nr[q]);
            float x0 = bf2f((unsigned short)(xp[q] & 0xffffu));
            float x1 = bf2f((unsigned short)(xp[q] >> 16));
            float y0 = bf2f((unsigned short)(yp[q] & 0xffffu));
            float y1 = bf2f((unsigned short)(yp[q] >> 16));
            float w0 = __expf(y0), w1 = __expf(y1);
            mg0 = fmaf(x0, nrm, mg0);
            mg1 = fmaf(x1, nrm, mg1);
            s0 += w0; s1 += w1;
            t0 = fmaf(y0, w0, t0);
            t1 = fmaf(y1, w1, t1);
        }
    }
    for (; i < end; ++i) {
        uint2 e0 = csr[i];
        size_t s_ = e0.x & 0x1FFFFu, r_ = e0.x >> 17;
        float nrm = __uint_as_float(e0.y);
        unsigned xp = *reinterpret_cast<const unsigned*>(Xb + s_ * 128 + c);
        unsigned yp = *reinterpret_cast<const unsigned*>(Y + (r_ * Nn + s_) * 128 + c);
        float x0 = bf2f((unsigned short)(xp & 0xffffu));
        float x1 = bf2f((unsigned short)(xp >> 16));
        float y0 = bf2f((unsigned short)(yp & 0xffffu));
        float y1 = bf2f((unsigned short)(yp >> 16));
        float w0 = __expf(y0), w1 = __expf(y1);
        mg0 = fmaf(x0, nrm, mg0);
        mg1 = fmaf(x1, nrm, mg1);
        s0 += w0; s1 += w1;
        t0 = fmaf(y0, w0, t0);
        t1 = fmaf(y1, w1, t1);
    }

    float o0 = mg0 + 0.1f * fmaxf(s0 > 0.f ? t0 / s0 : 0.f, 0.f);
    float o1 = mg1 + 0.1f * fmaxf(s1 > 0.f ? t1 / s1 : 0.f, 0.f);
    unsigned pk = (unsigned)f2bf(o0) | ((unsigned)f2bf(o1) << 16);
    *reinterpret_cast<unsigned*>(outb + (size_t)node * 128 + c) = pk;
}

// ---------- gather rows + exact gelu ----------
__global__ __launch_bounds__(256)
void gather_gelu(const float* __restrict__ h, const int* __restrict__ idx,
                 float* __restrict__ out, int M)
{
    int i = blockIdx.x * 256 + threadIdx.x;
    if (i >= M * 32) return;
    int row = i >> 5;
    int c = (i & 31) << 2;
    float4 v = *reinterpret_cast<const float4*>(h + (size_t)idx[row] * 128 + c);
    const float k = 0.7071067811865475f;
    v.x = 0.5f * v.x * (1.f + erff(v.x * k));
    v.y = 0.5f * v.y * (1.f + erff(v.y * k));
    v.z = 0.5f * v.z * (1.f + erff(v.z * k));
    v.w = 0.5f * v.w * (1.f + erff(v.w * k));
    reinterpret_cast<float4*>(out)[i] = v;
}

// ---------- launch ----------
extern "C" void kernel_launch(void* const* d_in, const int* in_sizes, int n_in,
                              void* d_out, int out_size, void* d_ws, size_t ws_size,
                              hipStream_t stream)
{
    const float* x      = (const float*)d_in[0];
    const int*   ei     = (const int*)d_in[1];
    const int*   et     = (const int*)d_in[2];
    // d_in[3] edge_weight: unused by the reference
    const int*   idxp   = (const int*)d_in[4];
    const float* proj_w = (const float*)d_in[5];
    const float* proj_b = (const float*)d_in[6];
    const float* bn_g   = (const float*)d_in[7];
    const float* bn_b   = (const float*)d_in[8];
    const float* win_w[2]  = {(const float*)d_in[9],  (const float*)d_in[14]};
    const float* win_b[2]  = {(const float*)d_in[10], (const float*)d_in[15]};
    const float* wrel[2]   = {(const float*)d_in[11], (const float*)d_in[16]};
    const float* cout_w[2] = {(const float*)d_in[12], (const float*)d_in[17]};
    const float* cout_b[2] = {(const float*)d_in[13], (const float*)d_in[18]};

    const int Nn  = in_sizes[0] / 128;
    const int E   = in_sizes[1] / 2;
    const int Mo  = in_sizes[4];
    const int nrel = in_sizes[11] / (128 * 128);
    const size_t ND = (size_t)Nn * 128;

    // workspace layout
    char* p = (char*)d_ws;
    float* h    = (float*)p;                  p += ND * 4;            // proj out / final out
    unsigned short* hb = (unsigned short*)p;  p += ND * 2;            // bf16 h (layer input)
    unsigned short* Xb = (unsigned short*)p;  p += ND * 2;            // bf16 xlin
    unsigned short* Yb = (unsigned short*)p;  p += (size_t)nrel * ND * 2;
    unsigned short* msgb = (unsigned short*)p; p += ND * 2;           // bf16 msg
    unsigned short* Wt = (unsigned short*)p;  p += (size_t)(4 + 2 * nrel) * 16384 * 2;
    uint2* csr  = (uint2*)p;                  p += (size_t)E * 8;
    float* dis  = (float*)p;                  p += (size_t)Nn * 4;
    int*   deg  = (int*)p;                    p += (size_t)Nn * 4;    // over src
    int*   cnt  = (int*)p;                    p += (size_t)Nn * 4;    // over dst (adjacent to deg)
    int*   rowptr = (int*)p;                  p += ((size_t)Nn + 1) * 4;
    int*   cursor = (int*)p;                  p += (size_t)Nn * 4;
    int*   bsum = (int*)p;                    p += 1024 * 4;
    float* bnsums = (float*)p;                p += 256 * 4;
    float* bnsc   = (float*)p;                p += 256 * 4;
    if ((size_t)(p - (char*)d_ws) > ws_size) return;

    const int WIN0 = 0, WIN1 = 1, COUT0 = 2, COUT1 = 3, WREL0 = 4;
    const int WREL1 = 4 + nrel;

    const int gemmGrid = (Nn + 63) / 64;
    const int mfmaGrid = (Nn + 127) / 128;
    const size_t n4 = ND / 4;
    const int n4grid = (int)((n4 + 255) / 256);
    const int nb = (Nn + 255) / 256;

    // ---- weight prep (independent of data path) ----
    wt_convert<<<4 + 2 * nrel, 256, 0, stream>>>(win_w[0], win_w[1], cout_w[0], cout_w[1],
                                                 wrel[0], wrel[1], Wt, nrel);

    // ---- stage 0: proj -> BN(batch stats) -> relu -> hb (bf16) ----
    gemm_f32<<<gemmGrid, 256, 0, stream>>>(x, proj_w, proj_b, h, Nn);
    hipMemsetAsync(bnsums, 0, 256 * 4, stream);
    hipMemsetAsync(deg, 0, (size_t)Nn * 8, stream);   // deg + cnt (adjacent)
    bn_stats<<<512, 256, 0, stream>>>(h, bnsums, Nn);
    bn_finalize<<<1, 128, 0, stream>>>(bnsums, bn_g, bn_b, bnsc, Nn);
    bn_apply_relu<<<n4grid, 256, 0, stream>>>(h, bnsc, hb, n4);

    // ---- CSR build (once; shared by both layers) ----
    deg_kernel<<<(E + 255) / 256, 256, 0, stream>>>(ei, deg, cnt, E);
    dis_kernel<<<(Nn + 255) / 256, 256, 0, stream>>>(deg, dis, Nn);
    scan_block_sums<<<nb, 256, 0, stream>>>(cnt, bsum, Nn);
    scan_offsets<<<1, 1024, 0, stream>>>(bsum, nb);
    scan_final<<<nb, 256, 0, stream>>>(cnt, bsum, rowptr, cursor, Nn, E);
    scatter_csr<<<(E + 255) / 256, 256, 0, stream>>>(ei, et, dis, cursor, csr, E);

    // ---- two DAN layers (all GEMMs via MFMA) ----
    for (int l = 0; l < 2; ++l) {
        // Xb = bf16(hb @ win + b)
        gemm_mfma<<<dim3(mfmaGrid, 1), 256, 0, stream>>>(
            hb, Wt + (size_t)(l == 0 ? WIN0 : WIN1) * 16384, win_b[l], nullptr, Xb, Nn);
        // Y[r] = Xb @ wrel[r]
        gemm_mfma<<<dim3(mfmaGrid, nrel), 256, 0, stream>>>(
            Xb, Wt + (size_t)(l == 0 ? WREL0 : WREL1) * 16384, nullptr, nullptr, Yb, Nn);
        // fused gather: gcn-sum + scatter-softmax + combine -> msgb (bf16)
        node_gather<<<(Nn + 3) / 4, 256, 0, stream>>>(rowptr, csr, Xb, Yb, msgb, Nn);
        // h(b) = msgb @ cout + b ; layer0 -> bf16 hb, layer1 -> f32 h
        if (l == 0)
            gemm_mfma<<<dim3(mfmaGrid, 1), 256, 0, stream>>>(
                msgb, Wt + (size_t)COUT0 * 16384, cout_b[0], nullptr, hb, Nn);
        else
            gemm_mfma<<<dim3(mfmaGrid, 1), 256, 0, stream>>>(
                msgb, Wt + (size_t)COUT1 * 16384, cout_b[1], h, nullptr, Nn);
    }

    gather_gelu<<<(Mo * 32 + 255) / 256, 256, 0, stream>>>(h, idxp, (float*)d_out, Mo);
}

// Round 6
// 481.987 us; speedup vs baseline: 16.6993x; 1.0516x over previous
//
#include <hip/hip_runtime.h>

#define HIST_BPG 32              // edge-slice blocks per (histogram, half) group
#define HIST_B   (HIST_BPG * 4)  // 4 groups: src-lo, src-hi, dst-lo, dst-hi

// ---------- helpers ----------
__device__ inline float bf2f(unsigned short u) {
    return __uint_as_float(((unsigned)u) << 16);
}
__device__ inline unsigned short f2bf(float f) {
    unsigned u = __float_as_uint(f);
    u += 0x7fffu + ((u >> 16) & 1u);   // round-to-nearest-even
    return (unsigned short)(u >> 16);
}

typedef __attribute__((ext_vector_type(8))) short short8v;   // 8 bf16 (4 VGPRs)
typedef __attribute__((ext_vector_type(4))) float f32x4;

// ================= device bodies =================

// ---- proj f32 GEMM body (tile = 64 rows); smem: As 33792 B + Ws 16384 B ----
__device__ void proj_body(char* smem, const float* __restrict__ A,
                          const float* __restrict__ W, const float* __restrict__ bias,
                          float* __restrict__ C, int M, int tile)
{
    float (*As)[132] = (float(*)[132])smem;
    float (*Ws)[128] = (float(*)[128])(smem + 33792);

    const int tid = threadIdx.x;
    const int row0 = tile * 64;

#pragma unroll
    for (int i = 0; i < 8; ++i) {
        int idx = tid + i * 256;
        int rr = idx >> 5;
        int cc = (idx & 31) << 2;
        int gr = row0 + rr;
        float4 v = make_float4(0.f, 0.f, 0.f, 0.f);
        if (gr < M) v = *reinterpret_cast<const float4*>(A + (size_t)gr * 128 + cc);
        *reinterpret_cast<float4*>(&As[rr][cc]) = v;
    }

    const int tx = tid & 15;
    const int ty = tid >> 4;
    float acc[4][8];
#pragma unroll
    for (int i = 0; i < 4; ++i)
#pragma unroll
        for (int j = 0; j < 8; ++j) acc[i][j] = 0.f;

    for (int kt = 0; kt < 4; ++kt) {
        __syncthreads();
#pragma unroll
        for (int i = 0; i < 4; ++i) {
            int idx = tid + i * 256;
            int rr = idx >> 5;
            int cc = (idx & 31) << 2;
            *reinterpret_cast<float4*>(&Ws[rr][cc]) =
                *reinterpret_cast<const float4*>(W + (size_t)(kt * 32 + rr) * 128 + cc);
        }
        __syncthreads();
#pragma unroll
        for (int kk = 0; kk < 32; ++kk) {
            const int k = kt * 32 + kk;
            float a0 = As[ty * 4 + 0][k];
            float a1 = As[ty * 4 + 1][k];
            float a2 = As[ty * 4 + 2][k];
            float a3 = As[ty * 4 + 3][k];
            float w[8];
#pragma unroll
            for (int j = 0; j < 8; ++j) w[j] = Ws[kk][tx + 16 * j];
#pragma unroll
            for (int j = 0; j < 8; ++j) {
                acc[0][j] = fmaf(a0, w[j], acc[0][j]);
                acc[1][j] = fmaf(a1, w[j], acc[1][j]);
                acc[2][j] = fmaf(a2, w[j], acc[2][j]);
                acc[3][j] = fmaf(a3, w[j], acc[3][j]);
            }
        }
    }

    float bb[8];
#pragma unroll
    for (int j = 0; j < 8; ++j) bb[j] = bias[tx + 16 * j];

#pragma unroll
    for (int i = 0; i < 4; ++i) {
        int gr = row0 + ty * 4 + i;
        if (gr >= M) continue;
#pragma unroll
        for (int j = 0; j < 8; ++j)
            C[(size_t)gr * 128 + tx + 16 * j] = acc[i][j] + bb[j];
    }
}

// ---- LDS-private histogram body (no global atomics) ----
// group g: 0=src-lo 1=src-hi 2=dst-lo 3=dst-hi ; 16-bit packed counts.
__device__ void hist_body(char* smem, const int* __restrict__ ei,
                          unsigned* __restrict__ partial, int Nn, int E,
                          int WORDS, int HALFR, int hbid)
{
    unsigned* sh = (unsigned*)smem;
    const int g = hbid / HIST_BPG;
    const int j = hbid - g * HIST_BPG;

    for (int w = threadIdx.x; w < WORDS; w += 256) sh[w] = 0;
    __syncthreads();

    const int* col = (g < 2) ? (ei + E) : ei;    // src column for deg, dst for cnt
    const int base = (g & 1) * HALFR;
    const size_t e0 = (size_t)E * j / HIST_BPG;
    const size_t e1 = (size_t)E * (j + 1) / HIST_BPG;
    for (size_t e = e0 + threadIdx.x; e < e1; e += 256) {
        int n = col[e] - base;
        if ((unsigned)n < (unsigned)HALFR)
            atomicAdd(&sh[n >> 1], 1u << ((n & 1) * 16));
    }
    __syncthreads();

    unsigned* out = partial + (size_t)hbid * WORDS;
    for (int w = threadIdx.x; w < WORDS; w += 256) out[w] = sh[w];
}

// ---- weight transpose+convert body ----
// layout: 0:win0 1:win1 2:cout0 3:cout1 4..3+nrel:wrel0 4+nrel..:wrel1
__device__ void wt_body(int mat, const float* __restrict__ win0, const float* __restrict__ win1,
                        const float* __restrict__ cout0, const float* __restrict__ cout1,
                        const float* __restrict__ wrel0, const float* __restrict__ wrel1,
                        unsigned short* __restrict__ Wt, int nrel)
{
    const float* W;
    if (mat == 0) W = win0;
    else if (mat == 1) W = win1;
    else if (mat == 2) W = cout0;
    else if (mat == 3) W = cout1;
    else if (mat < 4 + nrel) W = wrel0 + (size_t)(mat - 4) * 16384;
    else W = wrel1 + (size_t)(mat - 4 - nrel) * 16384;
    unsigned short* O = Wt + (size_t)mat * 16384;
    for (int i = threadIdx.x; i < 16384; i += 256) {
        int k = i >> 7, n = i & 127;
        O[(size_t)n * 128 + k] = f2bf(W[i]);
    }
}

// ---- MFMA GEMM body (operand-swapped; tile = 128 rows) ----
__device__ void mfma_body(const unsigned short* __restrict__ A,
                          const unsigned short* __restrict__ Wr,
                          const float* __restrict__ bias,
                          float* __restrict__ Cf, unsigned short* __restrict__ Cb,
                          int M, int tile)
{
    const int wave = threadIdx.x >> 6;
    const int lane = threadIdx.x & 63;
    const int row0 = tile * 128 + wave * 32;
    const int grp = lane >> 4;
    const int l16 = lane & 15;

    f32x4 acc[2][8] = {};

#pragma unroll
    for (int kt = 0; kt < 4; ++kt) {
        const int k0 = kt * 32 + grp * 8;
        short8v a[2];
#pragma unroll
        for (int m = 0; m < 2; ++m) {
            int r = row0 + 16 * m + l16;
            if (r > M - 1) r = M - 1;          // clamp; tail rows not stored
            a[m] = *reinterpret_cast<const short8v*>(A + (size_t)r * 128 + k0);
        }
#pragma unroll
        for (int n = 0; n < 8; ++n) {
            short8v b = *reinterpret_cast<const short8v*>(Wr + (size_t)(16 * n + l16) * 128 + k0);
            acc[0][n] = __builtin_amdgcn_mfma_f32_16x16x32_bf16(b, a[0], acc[0][n], 0, 0, 0);
            acc[1][n] = __builtin_amdgcn_mfma_f32_16x16x32_bf16(b, a[1], acc[1][n], 0, 0, 0);
        }
    }

    float4 bb[8];
#pragma unroll
    for (int n = 0; n < 8; ++n)
        bb[n] = bias ? *reinterpret_cast<const float4*>(bias + 16 * n + grp * 4)
                     : make_float4(0.f, 0.f, 0.f, 0.f);

#pragma unroll
    for (int m = 0; m < 2; ++m) {
        int row = row0 + 16 * m + l16;
        if (row >= M) continue;
#pragma unroll
        for (int n = 0; n < 8; ++n) {
            float v0 = acc[m][n][0] + bb[n].x;
            float v1 = acc[m][n][1] + bb[n].y;
            float v2 = acc[m][n][2] + bb[n].z;
            float v3 = acc[m][n][3] + bb[n].w;
            if (Cf) {
                *reinterpret_cast<float4*>(Cf + (size_t)row * 128 + 16 * n + grp * 4) =
                    make_float4(v0, v1, v2, v3);
            }
            if (Cb) {
                unsigned u0 = (unsigned)f2bf(v0) | ((unsigned)f2bf(v1) << 16);
                unsigned u1 = (unsigned)f2bf(v2) | ((unsigned)f2bf(v3) << 16);
                *reinterpret_cast<uint2*>(Cb + (size_t)row * 128 + 16 * n + grp * 4) =
                    make_uint2(u0, u1);
            }
        }
    }
}

// ---- bn stats body (256 stat-blocks) ----
__device__ void bn_stats_body(const float* __restrict__ h, float* __restrict__ sums,
                              int Nn, int b)
{
    const int c = threadIdx.x & 127;
    const int half = threadIdx.x >> 7;
    float s = 0.f, q = 0.f;
    for (int row = b * 2 + half; row < Nn; row += 512) {
        float v = h[(size_t)row * 128 + c];
        s += v;
        q += v * v;
    }
    __shared__ float ls[256], lq[256];
    ls[threadIdx.x] = s;
    lq[threadIdx.x] = q;
    __syncthreads();
    if (half == 0) {
        s += ls[threadIdx.x + 128];
        q += lq[threadIdx.x + 128];
        atomicAdd(&sums[c], s);
        atomicAdd(&sums[128 + c], q);
    }
}

// ---- scan bodies ----
__device__ void scan_block_sums_body(const int* __restrict__ cnt, int* __restrict__ bsum,
                                     int Nn, int b)
{
    __shared__ int sd[256];
    int tid = threadIdx.x;
    int i = b * 256 + tid;
    sd[tid] = i < Nn ? cnt[i] : 0;
    __syncthreads();
#pragma unroll
    for (int s = 128; s > 0; s >>= 1) {
        if (tid < s) sd[tid] += sd[tid + s];
        __syncthreads();
    }
    if (tid == 0) bsum[b] = sd[0];
}

__device__ void scan_offsets_body(int* __restrict__ bsum, int nb)   // nb <= 256
{
    __shared__ int sd[256];
    int tid = threadIdx.x;
    int v = tid < nb ? bsum[tid] : 0;
    sd[tid] = v;
    __syncthreads();
    for (int d = 1; d < 256; d <<= 1) {
        int t = tid >= d ? sd[tid - d] : 0;
        __syncthreads();
        sd[tid] += t;
        __syncthreads();
    }
    if (tid < nb) bsum[tid] = sd[tid] - v;   // exclusive
}

__device__ void scan_final_body(const int* __restrict__ cnt, const int* __restrict__ bsum,
                                int* __restrict__ rowptr, int* __restrict__ cursor,
                                int Nn, int E, int b)
{
    __shared__ int sd[256];
    int tid = threadIdx.x;
    int i = b * 256 + tid;
    int v = i < Nn ? cnt[i] : 0;
    sd[tid] = v;
    __syncthreads();
    for (int d = 1; d < 256; d <<= 1) {
        int t = tid >= d ? sd[tid - d] : 0;
        __syncthreads();
        sd[tid] += t;
        __syncthreads();
    }
    if (i < Nn) {
        int off = sd[tid] - v + bsum[b];
        rowptr[i] = off;
        cursor[i] = off;
    }
    if (b == 0 && tid == 0) rowptr[Nn] = E;
}

// ---- scatter body ----
__device__ void scatter_body(const int* __restrict__ ei, const int* __restrict__ et,
                             const float* __restrict__ dis, int* __restrict__ cursor,
                             uint2* __restrict__ csr, int E, int b)
{
    int e = b * 256 + threadIdx.x;
    if (e < E) {
        int dst = ei[e];
        int src = ei[E + e];
        int pos = atomicAdd(&cursor[dst], 1);
        float nrm = dis[dst] * dis[src];
        csr[pos] = make_uint2((unsigned)src | ((unsigned)et[e] << 17),
                              __float_as_uint(nrm));
    }
}

// ================= phase kernels =================

// K1: hist | wt_convert | proj
__global__ __launch_bounds__(256)
void k1_hist_wt_proj(const int* ei, unsigned* partial,
                     const float* x, const float* proj_w, const float* proj_b, float* h,
                     const float* win0, const float* win1,
                     const float* cout0, const float* cout1,
                     const float* wrel0, const float* wrel1, unsigned short* Wt,
                     int Nn, int E, int nrel, int WORDS, int HALFR)
{
    __shared__ __align__(16) char smem[50688];
    int bid = blockIdx.x;
    if (bid < HIST_B) { hist_body(smem, ei, partial, Nn, E, WORDS, HALFR, bid); return; }
    bid -= HIST_B;
    int nmat = 4 + 2 * nrel;
    if (bid < nmat) { wt_body(bid, win0, win1, cout0, cout1, wrel0, wrel1, Wt, nrel); return; }
    bid -= nmat;
    proj_body(smem, x, proj_w, proj_b, h, Nn, bid);
}

// K2: hist-reduce (-> dis, cnt) | bn_stats
__global__ __launch_bounds__(256)
void k2_reduce_bnstats(const unsigned* __restrict__ partial, float* __restrict__ dis,
                       int* __restrict__ cnt, const float* __restrict__ h,
                       float* __restrict__ bnsums, int Nn, int WORDS, int HALFR, int nRed)
{
    int bid = blockIdx.x;
    if (bid < nRed) {
        int t = bid * 256 + threadIdx.x;
        if (t < 4 * WORDS) {
            int histo = t / (2 * WORDS);
            int rem = t - histo * 2 * WORDS;
            int half = rem / WORDS;
            int w = rem - half * WORDS;
            int g = histo * 2 + half;
            unsigned slo = 0, shi = 0;
            const unsigned* p = partial + (size_t)(g * HIST_BPG) * WORDS + w;
#pragma unroll 4
            for (int j = 0; j < HIST_BPG; ++j) {
                unsigned u = p[(size_t)j * WORDS];
                slo += u & 0xffffu;
                shi += u >> 16;
            }
            int n0 = half * HALFR + 2 * w;
            int n1 = n0 + 1;
            if (histo == 0) {   // src degree -> dis
                if (n0 < Nn) dis[n0] = slo ? rsqrtf((float)slo) : 0.f;
                if (n1 < Nn) dis[n1] = shi ? rsqrtf((float)shi) : 0.f;
            } else {            // dst count -> cnt
                if (n0 < Nn) cnt[n0] = (int)slo;
                if (n1 < Nn) cnt[n1] = (int)shi;
            }
        }
        return;
    }
    bn_stats_body(h, bnsums, Nn, bid - nRed);
}

// K3: bn_finalize | scan_block_sums
__global__ __launch_bounds__(256)
void k3_bnfin_scan1(const float* __restrict__ sums, const float* __restrict__ g,
                    const float* __restrict__ b, float* __restrict__ sc,
                    const int* __restrict__ cnt, int* __restrict__ bsum, int Nn)
{
    if (blockIdx.x == 0) {
        int c = threadIdx.x;
        if (c < 128) {
            float inv = 1.f / (float)Nn;
            float mu = sums[c] * inv;
            float var = sums[128 + c] * inv - mu * mu;
            float rstd = rsqrtf(var + 1e-5f);
            float scale = rstd * g[c];
            sc[c] = scale;
            sc[128 + c] = b[c] - mu * scale;
        }
        return;
    }
    scan_block_sums_body(cnt, bsum, Nn, blockIdx.x - 1);
}

// K4: scan_offsets | bn_apply_relu (f32 -> bf16)
__global__ __launch_bounds__(256)
void k4_scanoff_bnapply(int* __restrict__ bsum, int nb,
                        const float* __restrict__ h, const float* __restrict__ sc,
                        unsigned short* __restrict__ hb, size_t n4)
{
    if (blockIdx.x == 0) { scan_offsets_body(bsum, nb); return; }
    size_t i = (size_t)(blockIdx.x - 1) * 256 + threadIdx.x;
    if (i >= n4) return;
    int c = (int)(i & 31) << 2;
    float4 v = reinterpret_cast<const float4*>(h)[i];
    float o0 = fmaxf(fmaf(v.x, sc[c + 0], sc[128 + c + 0]), 0.f);
    float o1 = fmaxf(fmaf(v.y, sc[c + 1], sc[128 + c + 1]), 0.f);
    float o2 = fmaxf(fmaf(v.z, sc[c + 2], sc[128 + c + 2]), 0.f);
    float o3 = fmaxf(fmaf(v.w, sc[c + 3], sc[128 + c + 3]), 0.f);
    ushort4 pk = make_ushort4(f2bf(o0), f2bf(o1), f2bf(o2), f2bf(o3));
    reinterpret_cast<ushort4*>(hb)[i] = pk;
}

// K5: win0 MFMA | scan_final (+cursor init)
__global__ __launch_bounds__(256)
void k5_win_scanfinal(const unsigned short* hb, const unsigned short* Wwin,
                      const float* winb, unsigned short* Xb, int M, int tiles,
                      const int* cnt, const int* bsum, int* rowptr, int* cursor,
                      int Nn, int E)
{
    if (blockIdx.x < (unsigned)tiles) {
        mfma_body(hb, Wwin, winb, nullptr, Xb, M, blockIdx.x);
        return;
    }
    scan_final_body(cnt, bsum, rowptr, cursor, Nn, E, blockIdx.x - tiles);
}

// K6: Y0 MFMA (nrel mats) interleaved with scatter_csr
__global__ __launch_bounds__(256)
void k6_y_scatter(const unsigned short* Xb, const unsigned short* Wrel,
                  unsigned short* Yb, int M, int tiles, int nrel,
                  const int* ei, const int* et, const float* dis,
                  int* cursor, uint2* csr, int E, int nS)
{
    const int nY = tiles * nrel;
    const int minv = nY < nS ? nY : nS;
    int bid = blockIdx.x;
    int yIdx = -1, sIdx = -1;
    if (bid < 2 * minv) {
        if ((bid & 1) == 0) yIdx = bid >> 1; else sIdx = bid >> 1;
    } else {
        int rem = bid - 2 * minv;
        if (nY > nS) yIdx = minv + rem; else sIdx = minv + rem;
    }
    if (yIdx >= 0) {
        int rel = yIdx / tiles;
        mfma_body(Xb, Wrel + (size_t)rel * 16384, nullptr, nullptr,
                  Yb + (size_t)rel * (size_t)M * 128, M, yIdx - rel * tiles);
    } else {
        scatter_body(ei, et, dis, cursor, csr, E, sIdx);
    }
}

// generic MFMA kernel (single or multi-mat)
__global__ __launch_bounds__(256)
void k_mfma(const unsigned short* A, const unsigned short* Wt0, const float* bias,
            float* Cf, unsigned short* Cb, int M, int tilesPerMat)
{
    int rel = blockIdx.x / tilesPerMat;
    int tile = blockIdx.x - rel * tilesPerMat;
    mfma_body(A, Wt0 + (size_t)rel * 16384, bias,
              Cf ? Cf + (size_t)rel * (size_t)M * 128 : nullptr,
              Cb ? Cb + (size_t)rel * (size_t)M * 128 : nullptr, M, tile);
}

// ---- fused per-node gather: gcn-sum + scatter-softmax + combine ----
// One wave per dst node; lane owns 2 channels. Clamped unroll-4 (no scalar
// tail) + csr double-buffer prefetch: 8 feature gathers in flight per step.
__global__ __launch_bounds__(256)
void node_gather(const int* __restrict__ rowptr, const uint2* __restrict__ csr,
                 const unsigned short* __restrict__ Xb,
                 const unsigned short* __restrict__ Y,
                 unsigned short* __restrict__ outb, int Nn)
{
    int node = blockIdx.x * 4 + (threadIdx.x >> 6);
    if (node >= Nn) return;
    int lane = threadIdx.x & 63;
    int c = lane << 1;

    int i = rowptr[node];
    const int end = rowptr[node + 1];

    if (i >= end) {   // isolated node
        *reinterpret_cast<unsigned*>(outb + (size_t)node * 128 + c) = 0u;
        return;
    }

    float mg0 = 0.f, mg1 = 0.f, s0 = 0.f, s1 = 0.f, t0 = 0.f, t1 = 0.f;

    uint2 cur[4];
#pragma unroll
    for (int q = 0; q < 4; ++q) cur[q] = csr[min(i + q, end - 1)];

    for (; i < end; i += 4) {
        uint2 nxt[4];
        const int ip = i + 4;
#pragma unroll
        for (int q = 0; q < 4; ++q) nxt[q] = csr[min(ip + q, end - 1)];

        unsigned xp[4], yp[4];
#pragma unroll
        for (int q = 0; q < 4; ++q) {
            size_t s_ = cur[q].x & 0x1FFFFu;
            size_t r_ = cur[q].x >> 17;
            xp[q] = *reinterpret_cast<const unsigned*>(Xb + s_ * 128 + c);
            yp[q] = *reinterpret_cast<const unsigned*>(Y + (r_ * Nn + s_) * 128 + c);
        }
#pragma unroll
        for (int q = 0; q < 4; ++q) {
            bool valid = (i + q) < end;
            float nrm = valid ? __uint_as_float(cur[q].y) : 0.f;
            float x0 = bf2f((unsigned short)(xp[q] & 0xffffu));
            float x1 = bf2f((unsigned short)(xp[q] >> 16));
            float y0 = bf2f((unsigned short)(yp[q] & 0xffffu));
            float y1 = bf2f((unsigned short)(yp[q] >> 16));
            float w0 = valid ? __expf(y0) : 0.f;
            float w1 = valid ? __expf(y1) : 0.f;
            mg0 = fmaf(x0, nrm, mg0);
            mg1 = fmaf(x1, nrm, mg1);
            s0 += w0; s1 += w1;
            t0 = fmaf(y0, w0, t0);
            t1 = fmaf(y1, w1, t1);
        }
#pragma unroll
        for (int q = 0; q < 4; ++q) cur[q] = nxt[q];
    }

    float o0 = mg0 + 0.1f * fmaxf(s0 > 0.f ? t0 / s0 : 0.f, 0.f);
    float o1 = mg1 + 0.1f * fmaxf(s1 > 0.f ? t1 / s1 : 0.f, 0.f);
    unsigned pk = (unsigned)f2bf(o0) | ((unsigned)f2bf(o1) << 16);
    *reinterpret_cast<unsigned*>(outb + (size_t)node * 128 + c) = pk;
}

// ---------- gather rows + exact gelu ----------
__global__ __launch_bounds__(256)
void gather_gelu(const float* __restrict__ h, const int* __restrict__ idx,
                 float* __restrict__ out, int M)
{
    int i = blockIdx.x * 256 + threadIdx.x;
    if (i >= M * 32) return;
    int row = i >> 5;
    int c = (i & 31) << 2;
    float4 v = *reinterpret_cast<const float4*>(h + (size_t)idx[row] * 128 + c);
    const float k = 0.7071067811865475f;
    v.x = 0.5f * v.x * (1.f + erff(v.x * k));
    v.y = 0.5f * v.y * (1.f + erff(v.y * k));
    v.z = 0.5f * v.z * (1.f + erff(v.z * k));
    v.w = 0.5f * v.w * (1.f + erff(v.w * k));
    reinterpret_cast<float4*>(out)[i] = v;
}

// ================= launch =================
extern "C" void kernel_launch(void* const* d_in, const int* in_sizes, int n_in,
                              void* d_out, int out_size, void* d_ws, size_t ws_size,
                              hipStream_t stream)
{
    const float* x      = (const float*)d_in[0];
    const int*   ei     = (const int*)d_in[1];
    const int*   et     = (const int*)d_in[2];
    // d_in[3] edge_weight: unused by the reference
    const int*   idxp   = (const int*)d_in[4];
    const float* proj_w = (const float*)d_in[5];
    const float* proj_b = (const float*)d_in[6];
    const float* bn_g   = (const float*)d_in[7];
    const float* bn_b   = (const float*)d_in[8];
    const float* win_w[2]  = {(const float*)d_in[9],  (const float*)d_in[14]};
    const float* win_b[2]  = {(const float*)d_in[10], (const float*)d_in[15]};
    const float* wrel[2]   = {(const float*)d_in[11], (const float*)d_in[16]};
    const float* cout_w[2] = {(const float*)d_in[12], (const float*)d_in[17]};
    const float* cout_b[2] = {(const float*)d_in[13], (const float*)d_in[18]};

    const int Nn  = in_sizes[0] / 128;
    const int E   = in_sizes[1] / 2;
    const int Mo  = in_sizes[4];
    const int nrel = in_sizes[11] / (128 * 128);
    const size_t ND = (size_t)Nn * 128;

    const int HALFR = ((Nn + 3) / 4) * 2;   // even; 2*HALFR >= Nn
    const int WORDS = HALFR / 2;            // packed 16-bit pairs
    if (WORDS > 12288) return;              // LDS budget guard (Nn <= ~49k)

    // workspace layout
    char* p = (char*)d_ws;
    float* h    = (float*)p;                  p += ND * 4;            // proj out / final out
    unsigned short* hb = (unsigned short*)p;  p += ND * 2;            // bf16 h (layer input)
    unsigned short* Xb = (unsigned short*)p;  p += ND * 2;            // bf16 xlin
    unsigned short* Yb = (unsigned short*)p;  p += (size_t)nrel * ND * 2;
    unsigned short* msgb = (unsigned short*)p; p += ND * 2;           // bf16 msg
    unsigned short* Wt = (unsigned short*)p;  p += (size_t)(4 + 2 * nrel) * 16384 * 2;
    uint2* csr  = (uint2*)p;                  p += (size_t)E * 8;
    unsigned* partial = (unsigned*)p;         p += (size_t)HIST_B * WORDS * 4;
    float* dis  = (float*)p;                  p += (size_t)Nn * 4;
    int*   cnt  = (int*)p;                    p += (size_t)Nn * 4;
    int*   rowptr = (int*)p;                  p += ((size_t)Nn + 1) * 4;
    int*   cursor = (int*)p;                  p += (size_t)Nn * 4;
    int*   bsum = (int*)p;                    p += 1024 * 4;
    float* bnsums = (float*)p;                p += 256 * 4;
    float* bnsc   = (float*)p;                p += 256 * 4;
    if ((size_t)(p - (char*)d_ws) > ws_size) return;

    const int WIN0 = 0, WIN1 = 1, COUT0 = 2, COUT1 = 3, WREL0 = 4;
    const int WREL1 = 4 + nrel;

    const int gemmGrid = (Nn + 63) / 64;          // proj tiles
    const int mfmaGrid = (Nn + 127) / 128;        // mfma tiles
    const size_t n4 = ND / 4;
    const int n4grid = (int)((n4 + 255) / 256);
    const int nb = (Nn + 255) / 256;              // scan blocks (<=256 required)
    const int nmat = 4 + 2 * nrel;
    const int nRed = (4 * WORDS + 255) / 256;     // hist-reduce blocks
    const int nS = (E + 255) / 256;               // scatter blocks
    const int nY = mfmaGrid * nrel;

    hipMemsetAsync(bnsums, 0, 256 * 4, stream);

    // K1: histogram | weight prep | proj GEMM
    k1_hist_wt_proj<<<HIST_B + nmat + gemmGrid, 256, 0, stream>>>(
        ei, partial, x, proj_w, proj_b, h,
        win_w[0], win_w[1], cout_w[0], cout_w[1], wrel[0], wrel[1], Wt,
        Nn, E, nrel, WORDS, HALFR);

    // K2: hist reduce (dis, cnt) | bn_stats
    k2_reduce_bnstats<<<nRed + 256, 256, 0, stream>>>(
        partial, dis, cnt, h, bnsums, Nn, WORDS, HALFR, nRed);

    // K3: bn_finalize | scan level-1
    k3_bnfin_scan1<<<1 + nb, 256, 0, stream>>>(bnsums, bn_g, bn_b, bnsc, cnt, bsum, Nn);

    // K4: scan offsets | bn apply+relu -> hb
    k4_scanoff_bnapply<<<1 + n4grid, 256, 0, stream>>>(bsum, nb, h, bnsc, hb, n4);

    // K5: win0 MFMA -> Xb | scan final (rowptr + cursor)
    k5_win_scanfinal<<<mfmaGrid + nb, 256, 0, stream>>>(
        hb, Wt + (size_t)WIN0 * 16384, win_b[0], Xb, Nn, mfmaGrid,
        cnt, bsum, rowptr, cursor, Nn, E);

    // K6: Y0 MFMA | scatter csr (interleaved)
    k6_y_scatter<<<nY + nS, 256, 0, stream>>>(
        Xb, Wt + (size_t)WREL0 * 16384, Yb, Nn, mfmaGrid, nrel,
        ei, et, dis, cursor, csr, E, nS);

    // layer 0 gather + cout
    node_gather<<<(Nn + 3) / 4, 256, 0, stream>>>(rowptr, csr, Xb, Yb, msgb, Nn);
    k_mfma<<<mfmaGrid, 256, 0, stream>>>(msgb, Wt + (size_t)COUT0 * 16384, cout_b[0],
                                         nullptr, hb, Nn, mfmaGrid);

    // layer 1
    k_mfma<<<mfmaGrid, 256, 0, stream>>>(hb, Wt + (size_t)WIN1 * 16384, win_b[1],
                                         nullptr, Xb, Nn, mfmaGrid);
    k_mfma<<<nY, 256, 0, stream>>>(Xb, Wt + (size_t)WREL1 * 16384, nullptr,
                                   nullptr, Yb, Nn, mfmaGrid);
    node_gather<<<(Nn + 3) / 4, 256, 0, stream>>>(rowptr, csr, Xb, Yb, msgb, Nn);
    k_mfma<<<mfmaGrid, 256, 0, stream>>>(msgb, Wt + (size_t)COUT1 * 16384, cout_b[1],
                                         h, nullptr, Nn, mfmaGrid);

    gather_gelu<<<(Mo * 32 + 255) / 256, 256, 0, stream>>>(h, idxp, (float*)d_out, Mo);
}